// Round 1
// baseline (1554.114 us; speedup 1.0000x reference)
//
#include <hip/hip_runtime.h>
#include <hip/hip_bf16.h>

typedef __bf16 bf16_t;
typedef __bf16 bf16x8 __attribute__((ext_vector_type(8)));
typedef float floatx4 __attribute__((ext_vector_type(4)));

#define D_MODEL 768
#define D_INNER 1536
#define D_STATE 16
#define DT_RANK 48
#define NROWS 2048   /* B*L */
#define LSEQ 1024

// ---------------------------------------------------------------------------
// Input dtype detection: ln_w is all-ones. fp32 -> first word 0x3F800000,
// bf16 -> 0x3F803F80. flag: 1 = inputs are bf16, 0 = inputs are fp32.
// Round-2 evidence: flag==0 on this harness (inputs fp32).
// ---------------------------------------------------------------------------
__global__ void detect_kernel(const unsigned int* __restrict__ lnw, int* __restrict__ flag) {
  if (threadIdx.x == 0 && blockIdx.x == 0)
    *flag = (lnw[0] == 0x3F800000u) ? 0 : 1;
}

// ---------------------------------------------------------------------------
// Merged canonicalizer: all 11 weight tensors -> contiguous bf16 wk buffer.
// (Was 13 separate tiny launches; 1 launch saves serialization overhead.)
// ---------------------------------------------------------------------------
struct CvtSrcs { const void* p[11]; };

__global__ __launch_bounds__(256) void cvt_all(CvtSrcs sp, bf16_t* __restrict__ wk,
                                               int total, const int* __restrict__ flagp) {
  int i = blockIdx.x * 256 + threadIdx.x;
  if (i >= total) return;
  const int off[12] = {0, 4718592, 4730880, 4733952, 4979712, 5127168, 5130240,
                       5179392, 5182464, 7541760, 7542528, 7543296};
  const void* src = sp.p[0];
  int base = 0;
#pragma unroll
  for (int k = 1; k <= 10; k++) {
    if (i >= off[k]) { src = sp.p[k]; base = off[k]; }
  }
  int j = i - base;
  float v = (*flagp) ? (float)((const bf16_t*)src)[j] : ((const float*)src)[j];
  wk[i] = (bf16_t)v;
}

// ---------------------------------------------------------------------------
// Embedding gather: h (f32 residual stream) and hb (bf16 GEMM A-operand).
// ---------------------------------------------------------------------------
__global__ __launch_bounds__(256) void embed_kernel(const int* __restrict__ x,
                                                    const void* __restrict__ emb,
                                                    float* __restrict__ h,
                                                    bf16_t* __restrict__ hb,
                                                    const int* __restrict__ flagp) {
  int isbf = *flagp;
  int idx = blockIdx.x * 256 + threadIdx.x;           // 2048*768
  if (idx >= NROWS * D_MODEL) return;
  int row = idx / D_MODEL, c = idx - row * D_MODEL;
  size_t o = (size_t)x[row] * D_MODEL + c;
  float v = isbf ? (float)((const bf16_t*)emb)[o] : ((const float*)emb)[o];
  h[idx] = v;
  hb[idx] = (bf16_t)v;
}

// ---------------------------------------------------------------------------
// MFMA GEMM: C(M,N) = A(M,K) * Bw(N,K)^T. A always bf16. Bw bf16, unless
// flagp!=null and *flagp==0 -> Bw is fp32 (converted during LDS staging).
// 128x128 tile, BK=32, 4 waves x (64x64 = 4x4 MFMA 16x16x32).
// mode 0: Cf = acc (f32)          [in_proj -> xz]
// mode 1: v=acc+res; Cf=v, Cb=v   [out_proj + residual -> h, hb]
// mode 2: Cf = acc (f32)          [logits -- OUTPUT IS FP32]
// swapgrid: m-block index taken from blockIdx.x (fastest) so that blocks
// sharing the same B panel are dispatch-adjacent -> per-XCD L2 reuse of B.
// Layouts (m89/m91): A frag [m=lane&15][k=(lane>>4)*8+j], B mirrored n=lane&15,
// D col=lane&15, row=(lane>>4)*4+reg.
// ---------------------------------------------------------------------------
__global__ __launch_bounds__(256) void gemm_bt(const bf16_t* __restrict__ A,
                                               const void* __restrict__ Bw,
                                               int M, int N, int K, int mode,
                                               float* __restrict__ Cf,
                                               bf16_t* __restrict__ Cb,
                                               const float* __restrict__ res,
                                               const int* __restrict__ flagp,
                                               int swapgrid) {
  __shared__ __align__(16) bf16_t As[128][40];  // 80B row stride: 16B-aligned, 2-way banks (free)
  __shared__ __align__(16) bf16_t Bs[128][40];
  int bNative = flagp ? (*flagp == 0) : 0;      // 1 -> Bw is fp32
  int tid = threadIdx.x;
  int nb = swapgrid ? blockIdx.y : blockIdx.x;
  int mb = swapgrid ? blockIdx.x : blockIdx.y;
  int m0 = mb * 128, n0 = nb * 128;
  int wave = tid >> 6, lane = tid & 63;
  int wr = wave >> 1, wc = wave & 1;
  int m16 = lane & 15, ksel = lane >> 4;

  floatx4 acc[4][4];
#pragma unroll
  for (int i = 0; i < 4; i++)
#pragma unroll
    for (int j = 0; j < 4; j++) acc[i][j] = (floatx4){0.f, 0.f, 0.f, 0.f};

  for (int k0 = 0; k0 < K; k0 += 32) {
#pragma unroll
    for (int rep = 0; rep < 2; ++rep) {
      int l = tid + rep * 256;
      int row = l >> 2, seg = l & 3;
      size_t offA = (size_t)(m0 + row) * K + k0 + seg * 8;
      *(uint4*)(&As[row][seg * 8]) = *(const uint4*)(A + offA);
      size_t offB = (size_t)(n0 + row) * K + k0 + seg * 8;
      if (!bNative) {
        *(uint4*)(&Bs[row][seg * 8]) = *(const uint4*)((const bf16_t*)Bw + offB);
      } else {
        const float* bf = (const float*)Bw + offB;
        float4 f0 = *(const float4*)bf;
        float4 f1 = *(const float4*)(bf + 4);
        bf16_t* d = &Bs[row][seg * 8];
        d[0] = (bf16_t)f0.x; d[1] = (bf16_t)f0.y; d[2] = (bf16_t)f0.z; d[3] = (bf16_t)f0.w;
        d[4] = (bf16_t)f1.x; d[5] = (bf16_t)f1.y; d[6] = (bf16_t)f1.z; d[7] = (bf16_t)f1.w;
      }
    }
    __syncthreads();
    bf16x8 aF[4], bF[4];
#pragma unroll
    for (int mi = 0; mi < 4; mi++)
      aF[mi] = *(const bf16x8*)(&As[wr * 64 + mi * 16 + m16][ksel * 8]);
#pragma unroll
    for (int ni = 0; ni < 4; ni++)
      bF[ni] = *(const bf16x8*)(&Bs[wc * 64 + ni * 16 + m16][ksel * 8]);
#pragma unroll
    for (int mi = 0; mi < 4; mi++)
#pragma unroll
      for (int ni = 0; ni < 4; ni++)
        acc[mi][ni] = __builtin_amdgcn_mfma_f32_16x16x32_bf16(aF[mi], bF[ni], acc[mi][ni], 0, 0, 0);
    __syncthreads();
  }

#pragma unroll
  for (int mi = 0; mi < 4; mi++)
#pragma unroll
    for (int ni = 0; ni < 4; ni++)
#pragma unroll
      for (int r = 0; r < 4; r++) {
        int row = m0 + wr * 64 + mi * 16 + ksel * 4 + r;
        int col = n0 + wc * 64 + ni * 16 + m16;
        size_t off = (size_t)row * N + col;
        float v = acc[mi][ni][r];
        if (mode == 0) {
          Cf[off] = v;
        } else if (mode == 1) {
          float o = v + res[off];
          Cf[off] = o;
          Cb[off] = (bf16_t)o;
        } else {
          Cf[off] = v;            // fp32 logits
        }
      }
}

// ---------------------------------------------------------------------------
// Depthwise causal conv1d (K=4) + bias + SiLU. x_in = xz[:, 0:1536] (f32).
// ---------------------------------------------------------------------------
__global__ __launch_bounds__(256) void conv_silu(const float* __restrict__ xz,
                                                 const bf16_t* __restrict__ cw,
                                                 const bf16_t* __restrict__ cb,
                                                 bf16_t* __restrict__ xc) {
  int idx = blockIdx.x * 256 + threadIdx.x;   // NROWS*D_INNER
  if (idx >= NROWS * D_INNER) return;
  int d = idx % D_INNER;
  int row = idx / D_INNER;
  int l = row % LSEQ;
  int base = row - l;                         // start row of this batch
  float s = (float)cb[d];
#pragma unroll
  for (int k = 0; k < 4; k++) {
    int ll = l - 3 + k;
    if (ll >= 0) s += (float)cw[d * 4 + k] * xz[(size_t)(base + ll) * (2 * D_INNER) + d];
  }
  float sil = s / (1.f + __expf(-s));
  xc[idx] = (bf16_t)sil;
}

// ---------------------------------------------------------------------------
// x_proj: x_dbl(2048,80) = xc(2048,1536) @ W(80,1536)^T. One block per row.
// ---------------------------------------------------------------------------
__device__ inline float bflo(unsigned int u) { return __uint_as_float(u << 16); }
__device__ inline float bfhi(unsigned int u) { return __uint_as_float(u & 0xffff0000u); }

__global__ __launch_bounds__(128) void xproj_kernel(const bf16_t* __restrict__ xc,
                                                    const bf16_t* __restrict__ W,
                                                    float* __restrict__ xdbl) {
  __shared__ unsigned int srow[D_INNER / 2];
  int row = blockIdx.x;
  const unsigned int* src = (const unsigned int*)(xc + (size_t)row * D_INNER);
  for (int i = threadIdx.x; i < D_INNER / 2; i += 128) srow[i] = src[i];
  __syncthreads();
  int j = threadIdx.x;
  if (j < DT_RANK + 2 * D_STATE) {
    const unsigned int* wr = (const unsigned int*)(W + (size_t)j * D_INNER);
    float s = 0.f;
    for (int i = 0; i < D_INNER / 2; i++) {
      unsigned int a = srow[i], w = wr[i];
      s = fmaf(bflo(a), bflo(w), s);
      s = fmaf(bfhi(a), bfhi(w), s);
    }
    xdbl[(size_t)row * 80 + j] = s;
  }
}

// ---------------------------------------------------------------------------
// dt_proj + softplus: dt(2048,1536) = softplus(x_dbl[:, :48] @ W(1536,48)^T + b)
// ---------------------------------------------------------------------------
__global__ __launch_bounds__(256) void dtproj_kernel(const float* __restrict__ xdbl,
                                                     const bf16_t* __restrict__ W,
                                                     const bf16_t* __restrict__ bias,
                                                     float* __restrict__ dt) {
  int idx = blockIdx.x * 256 + threadIdx.x;  // NROWS*D_INNER
  if (idx >= NROWS * D_INNER) return;
  int d = idx % D_INNER;
  int row = idx / D_INNER;
  const bf16_t* wr = W + (size_t)d * DT_RANK;
  const float* xr = xdbl + (size_t)row * 80;
  float s = (float)bias[d];
#pragma unroll 8
  for (int r = 0; r < DT_RANK; r++) s = fmaf(xr[r], (float)wr[r], s);
  float sp = (s > 20.f) ? s : log1pf(__expf(s));
  dt[idx] = sp;
}

// ---------------------------------------------------------------------------
// Selective scan fused with D-skip and SiLU(z) gating -> yg (bf16).
// One lane per (b,d,n); 16-lane reduce over n via DPP (VALU-only, no LDS
// latency: quad_perm xor1/xor2 + row_ror:4/8 -- lane n==0 gets the exact
// same rounding order as the previous shfl_xor butterfly).
// Depth-8 software pipeline on the per-row loads (dt/u/B/C/z): with <1
// wave/SIMD there is no TLP, so L2 latency (~200cy, new cacheline each
// iteration) must be hidden by ILP. Ring buffers are compile-time indexed
// (chunked-by-8 loop). Over-reads past the last row land in later scratch
// regions of d_out (valid memory) and are discarded.
// 64-thread blocks -> 768 blocks: all 256 CUs active (was 192 blocks).
// ---------------------------------------------------------------------------
template <int CTRL>
__device__ __forceinline__ float dpp_perm(float x) {
  return __int_as_float(
      __builtin_amdgcn_update_dpp(0, __float_as_int(x), CTRL, 0xf, 0xf, false));
}

__global__ __launch_bounds__(64) void scan_kernel(const float* __restrict__ dt,
                                                  const bf16_t* __restrict__ xc,
                                                  const float* __restrict__ xdbl,
                                                  const float* __restrict__ xz,
                                                  const bf16_t* __restrict__ A_log,
                                                  const bf16_t* __restrict__ Dp,
                                                  bf16_t* __restrict__ yg) {
  int tid = threadIdx.x;
  int chan = blockIdx.x * 4 + (tid >> 4);    // 0..3071
  int b = chan / D_INNER, d = chan - (chan / D_INNER) * D_INNER;
  int n = tid & 15;
  float Adn = -__expf((float)A_log[d * D_STATE + n]);
  float Dd = (float)Dp[d];
  float h = 0.f;
  size_t baseRow = (size_t)b * LSEQ;

  float pd[8], pu[8], pB[8], pC[8], pz[8];
#pragma unroll
  for (int q = 0; q < 8; q++) {
    size_t r = baseRow + q;
    pd[q] = dt[r * D_INNER + d];
    pu[q] = (float)xc[r * D_INNER + d];
    pB[q] = xdbl[r * 80 + DT_RANK + n];
    pC[q] = xdbl[r * 80 + DT_RANK + D_STATE + n];
    pz[q] = (n == 0) ? xz[r * (2 * D_INNER) + D_INNER + d] : 0.f;
  }

  for (int l0 = 0; l0 < LSEQ; l0 += 8) {
#pragma unroll
    for (int q = 0; q < 8; q++) {
      size_t r = baseRow + l0 + q;
      float dtv = pd[q], uv = pu[q], Bv = pB[q], Cv = pC[q], zv = pz[q];
      // prefetch row r+8 into slot q (compile-time index)
      size_t rp = r + 8;
      pd[q] = dt[rp * D_INNER + d];
      pu[q] = (float)xc[rp * D_INNER + d];
      pB[q] = xdbl[rp * 80 + DT_RANK + n];
      pC[q] = xdbl[rp * 80 + DT_RANK + D_STATE + n];
      pz[q] = (n == 0) ? xz[rp * (2 * D_INNER) + D_INNER + d] : 0.f;

      float dA = __expf(dtv * Adn);
      h = fmaf(dA, h, dtv * Bv * uv);
      float p = h * Cv;
      p += dpp_perm<0xB1>(p);    // quad_perm [1,0,3,2]  (xor 1)
      p += dpp_perm<0x4E>(p);    // quad_perm [2,3,0,1]  (xor 2)
      p += dpp_perm<0x124>(p);   // row_ror:4
      p += dpp_perm<0x128>(p);   // row_ror:8
      if (n == 0) {
        float sil = zv / (1.f + __expf(-zv));
        float y = (p + Dd * uv) * sil;
        yg[r * D_INNER + d] = (bf16_t)y;
      }
    }
  }
}

// ---------------------------------------------------------------------------
// LayerNorm over 768, bf16 out (logits A-operand).
// ---------------------------------------------------------------------------
__global__ __launch_bounds__(256) void ln_kernel(const float* __restrict__ h,
                                                 const bf16_t* __restrict__ w,
                                                 const bf16_t* __restrict__ b,
                                                 bf16_t* __restrict__ out) {
  __shared__ float s1[4], s2[4];
  int row = blockIdx.x;
  int tid = threadIdx.x, lane = tid & 63, wave = tid >> 6;
  const float* hr = h + (size_t)row * D_MODEL;
  float a = 0.f, a2 = 0.f;
  for (int i = tid; i < D_MODEL; i += 256) {
    float v = hr[i];
    a += v; a2 += v * v;
  }
#pragma unroll
  for (int m = 32; m >= 1; m >>= 1) {
    a += __shfl_xor(a, m, 64);
    a2 += __shfl_xor(a2, m, 64);
  }
  if (lane == 0) { s1[wave] = a; s2[wave] = a2; }
  __syncthreads();
  float sum = s1[0] + s1[1] + s1[2] + s1[3];
  float sum2 = s2[0] + s2[1] + s2[2] + s2[3];
  float mu = sum / D_MODEL;
  float var = sum2 / D_MODEL - mu * mu;
  float inv = rsqrtf(var + 1e-5f);
  for (int i = tid; i < D_MODEL; i += 256)
    out[(size_t)row * D_MODEL + i] = (bf16_t)((hr[i] - mu) * inv * (float)w[i] + (float)b[i]);
}

// ---------------------------------------------------------------------------
extern "C" void kernel_launch(void* const* d_in, const int* in_sizes, int n_in,
                              void* d_out, int out_size, void* d_ws, size_t ws_size,
                              hipStream_t stream) {
  const int* x = (const int*)d_in[0];
  const void* emb = d_in[1];
  float* out = (float*)d_out;                    // OUTPUT IS FP32 (reference dtype)

  // --- scratch inside d_out (dead before the final logits GEMM writes it) ---
  // d_out = 2048*32000 fp32 = 262 MB; scratch uses the first 75.5 MB.
  char* ob = (char*)d_out;
  float* h = (float*)(ob + 0);                   //  6,291,456 B
  bf16_t* hb = (bf16_t*)(ob + 6291456);          //  3,145,728 B
  float* xz = (float*)(ob + 9437184);            // 25,165,824 B
  bf16_t* xc = (bf16_t*)(ob + 34603008);         //  6,291,456 B
  float* xdbl = (float*)(ob + 40894464);         //    655,360 B
  float* dt = (float*)(ob + 41549824);           // 12,582,912 B
  bf16_t* yg = (bf16_t*)(ob + 54132736);         //  6,291,456 B
  bf16_t* wk = (bf16_t*)(ob + 60424192);         // 15,086,592 B canonical bf16 weights
  // --- d_ws: logits A-operand (must survive logits GEMM) + dtype flag ---
  bf16_t* lno = (bf16_t*)d_ws;                   //  3,145,728 B
  int* flag = (int*)((char*)d_ws + 3145728);

  // canonical weight layout (element offsets into wk)
  bf16_t* c_inw  = wk + 0;          // 2*3072*768 = 4,718,592
  bf16_t* c_cw   = wk + 4718592;    // 12,288
  bf16_t* c_cb   = wk + 4730880;    // 3,072
  bf16_t* c_xpw  = wk + 4733952;    // 245,760
  bf16_t* c_dtw  = wk + 4979712;    // 147,456
  bf16_t* c_dtb  = wk + 5127168;    // 3,072
  bf16_t* c_alog = wk + 5130240;    // 49,152
  bf16_t* c_dp   = wk + 5179392;    // 3,072
  bf16_t* c_outw = wk + 5182464;    // 2,359,296
  bf16_t* c_lnw  = wk + 7541760;    // 768
  bf16_t* c_lnb  = wk + 7542528;    // 768

  detect_kernel<<<1, 64, 0, stream>>>((const unsigned int*)d_in[11], flag);

  CvtSrcs srcs;
  for (int k = 0; k < 11; k++) srcs.p[k] = d_in[k + 2];
  const int cvt_total = 7543296;
  cvt_all<<<(cvt_total + 255) / 256, 256, 0, stream>>>(srcs, wk, cvt_total, flag);

  embed_kernel<<<(NROWS * D_MODEL + 255) / 256, 256, 0, stream>>>(x, emb, h, hb, flag);

  for (int i = 0; i < 2; i++) {
    gemm_bt<<<dim3(3072 / 128, NROWS / 128), 256, 0, stream>>>(
        hb, c_inw + (size_t)i * 2 * D_INNER * D_MODEL, NROWS, 2 * D_INNER, D_MODEL,
        0, xz, nullptr, nullptr, nullptr, 0);
    conv_silu<<<(NROWS * D_INNER + 255) / 256, 256, 0, stream>>>(
        xz, c_cw + (size_t)i * D_INNER * 4, c_cb + (size_t)i * D_INNER, xc);
    xproj_kernel<<<NROWS, 128, 0, stream>>>(xc, c_xpw + (size_t)i * 80 * D_INNER, xdbl);
    dtproj_kernel<<<(NROWS * D_INNER + 255) / 256, 256, 0, stream>>>(
        xdbl, c_dtw + (size_t)i * D_INNER * DT_RANK, c_dtb + (size_t)i * D_INNER, dt);
    scan_kernel<<<(2 * D_INNER) / 4, 64, 0, stream>>>(
        dt, xc, xdbl, xz, c_alog + (size_t)i * D_INNER * D_STATE, c_dp + (size_t)i * D_INNER, yg);
    gemm_bt<<<dim3(D_MODEL / 128, NROWS / 128), 256, 0, stream>>>(
        yg, c_outw + (size_t)i * D_MODEL * D_INNER, NROWS, D_MODEL, D_INNER,
        1, h, hb, h, nullptr, 0);
  }

  ln_kernel<<<NROWS, 256, 0, stream>>>(h, c_lnw, c_lnb, lno);

  // logits (fp32) = lno @ emb^T (emb in native dtype -> adaptive B staging)
  // swapgrid=1: m-blocks fastest so the 16 sharers of each B panel are
  // dispatch-adjacent (2 per XCD) -> B panel read once per XCD L2.
  gemm_bt<<<dim3(NROWS / 128, 32000 / 128), 256, 0, stream>>>(
      lno, emb, NROWS, 32000, D_MODEL, 2, out, nullptr, nullptr, flag, 1);
}

// Round 2
// 1318.584 us; speedup vs baseline: 1.1786x; 1.1786x over previous
//
#include <hip/hip_runtime.h>
#include <hip/hip_bf16.h>

typedef __bf16 bf16_t;
typedef __bf16 bf16x8 __attribute__((ext_vector_type(8)));
typedef float floatx4 __attribute__((ext_vector_type(4)));

#define D_MODEL 768
#define D_INNER 1536
#define D_STATE 16
#define DT_RANK 48
#define NROWS 2048   /* B*L */
#define LSEQ 1024

// ---------------------------------------------------------------------------
// Input dtype detection: ln_w is all-ones. fp32 -> first word 0x3F800000,
// bf16 -> 0x3F803F80. flag: 1 = inputs are bf16, 0 = inputs are fp32.
// Measured: flag==0 on this harness (inputs fp32).
// ---------------------------------------------------------------------------
__global__ void detect_kernel(const unsigned int* __restrict__ lnw, int* __restrict__ flag) {
  if (threadIdx.x == 0 && blockIdx.x == 0)
    *flag = (lnw[0] == 0x3F800000u) ? 0 : 1;
}

// ---------------------------------------------------------------------------
// Merged canonicalizer: all 11 weight tensors -> contiguous bf16 wk buffer.
// ---------------------------------------------------------------------------
struct CvtSrcs { const void* p[11]; };

__global__ __launch_bounds__(256) void cvt_all(CvtSrcs sp, bf16_t* __restrict__ wk,
                                               int total, const int* __restrict__ flagp) {
  int i = blockIdx.x * 256 + threadIdx.x;
  if (i >= total) return;
  const int off[12] = {0, 4718592, 4730880, 4733952, 4979712, 5127168, 5130240,
                       5179392, 5182464, 7541760, 7542528, 7543296};
  const void* src = sp.p[0];
  int base = 0;
#pragma unroll
  for (int k = 1; k <= 10; k++) {
    if (i >= off[k]) { src = sp.p[k]; base = off[k]; }
  }
  int j = i - base;
  float v = (*flagp) ? (float)((const bf16_t*)src)[j] : ((const float*)src)[j];
  wk[i] = (bf16_t)v;
}

// ---------------------------------------------------------------------------
// Optional: full embedding table -> bf16 (only if d_ws is big enough).
// Removes the fp32-B staging path from the logits GEMM entirely.
// ---------------------------------------------------------------------------
__global__ __launch_bounds__(256) void cvt_emb(const void* __restrict__ src,
                                               bf16_t* __restrict__ dst,
                                               const int* __restrict__ flagp) {
  int i = blockIdx.x * 256 + threadIdx.x;      // chunk of 8 elements
  const int nchunk = 32000 * 768 / 8;
  if (i >= nchunk) return;
  if (*flagp) {
    ((uint4*)dst)[i] = ((const uint4*)src)[i];
  } else {
    const float4* s = (const float4*)src + (size_t)i * 2;
    float4 f0 = s[0], f1 = s[1];
    bf16x8 v;
    v[0] = (bf16_t)f0.x; v[1] = (bf16_t)f0.y; v[2] = (bf16_t)f0.z; v[3] = (bf16_t)f0.w;
    v[4] = (bf16_t)f1.x; v[5] = (bf16_t)f1.y; v[6] = (bf16_t)f1.z; v[7] = (bf16_t)f1.w;
    *(bf16x8*)(dst + (size_t)i * 8) = v;
  }
}

// ---------------------------------------------------------------------------
// Embedding gather: h (f32 residual stream) and hb (bf16 GEMM A-operand).
// ---------------------------------------------------------------------------
__global__ __launch_bounds__(256) void embed_kernel(const int* __restrict__ x,
                                                    const void* __restrict__ emb,
                                                    float* __restrict__ h,
                                                    bf16_t* __restrict__ hb,
                                                    const int* __restrict__ flagp) {
  int isbf = *flagp;
  int idx = blockIdx.x * 256 + threadIdx.x;           // 2048*768
  if (idx >= NROWS * D_MODEL) return;
  int row = idx / D_MODEL, c = idx - row * D_MODEL;
  size_t o = (size_t)x[row] * D_MODEL + c;
  float v = isbf ? (float)((const bf16_t*)emb)[o] : ((const float*)emb)[o];
  h[idx] = v;
  hb[idx] = (bf16_t)v;
}

// ---------------------------------------------------------------------------
// MFMA GEMM: C(M,N) = A(M,K) * Bw(N,K)^T. A always bf16 (16B-aligned rows).
// K must be a multiple of 64 (768 / 1536 here).
// Structure (m97-tier): BK=64, linear LDS [128][64] bf16, staged via
// global_load_lds dwordx4 with XOR chunk swizzle applied on the GLOBAL
// source and on the ds_read (rule 21: linear dest + inverse-swz source +
// swz read; XOR is its own inverse). chunk(row, c) holds K-seg c^(row&7),
// so the fragment read of K-seg t hits chunk t^(row&7) -> 16 lanes of a
// ds_read_b128 group land on all 8 bank groups (conflict-spread).
// B fp32 fallback (flagp && *flagp==0): float4x2 -> bf16x8 -> single
// ds_write_b128 at the swizzled chunk (no scalar b16 writes).
// mode 0: Cf = acc (f32)          [in_proj -> xz]
// mode 1: v=acc+res; Cf=v, Cb=v   [out_proj + residual -> h, hb]
// mode 2: Cf = acc (f32)          [logits -- OUTPUT IS FP32]
// swapgrid: m-block index fastest -> B-panel sharers dispatch-adjacent.
// ---------------------------------------------------------------------------
typedef __attribute__((address_space(3))) void lds_void_t;
typedef __attribute__((address_space(1))) void glb_void_t;

__device__ __forceinline__ void gload16(const void* g, void* l) {
  __builtin_amdgcn_global_load_lds((const glb_void_t*)(unsigned long long)g,
                                   (lds_void_t*)(unsigned long long)l, 16, 0, 0);
}

__global__ __launch_bounds__(256) void gemm_bt(const bf16_t* __restrict__ A,
                                               const void* __restrict__ Bw,
                                               int M, int N, int K, int mode,
                                               float* __restrict__ Cf,
                                               bf16_t* __restrict__ Cb,
                                               const float* __restrict__ res,
                                               const int* __restrict__ flagp,
                                               int swapgrid) {
  __shared__ __align__(16) bf16_t As[128 * 64];
  __shared__ __align__(16) bf16_t Bs[128 * 64];
  int bNative = flagp ? (*flagp == 0) : 0;      // 1 -> Bw is fp32
  int tid = threadIdx.x;
  int nb = swapgrid ? blockIdx.y : blockIdx.x;
  int mb = swapgrid ? blockIdx.x : blockIdx.y;
  int m0 = mb * 128, n0 = nb * 128;
  int wave = tid >> 6, lane = tid & 63;
  int wr = wave >> 1, wc = wave & 1;
  int m16 = lane & 15, ksel = lane >> 4;
  int srow = lane >> 3;                         // 0..7 within an 8-row slab
  int sseg = lane & 7;

  floatx4 acc[4][4];
#pragma unroll
  for (int i = 0; i < 4; i++)
#pragma unroll
    for (int j = 0; j < 4; j++) acc[i][j] = (floatx4){0.f, 0.f, 0.f, 0.f};

  for (int k0 = 0; k0 < K; k0 += 64) {
    // ---- stage A (always bf16): 16KB = 16 slabs of 1KB; wave w -> slabs w*4..w*4+3
#pragma unroll
    for (int i = 0; i < 4; i++) {
      int j = wave * 4 + i;
      int row = j * 8 + srow;
      int sg = sseg ^ (row & 7);
      gload16(A + (size_t)(m0 + row) * K + k0 + sg * 8, &As[j * 512]);
    }
    if (!bNative) {
#pragma unroll
      for (int i = 0; i < 4; i++) {
        int j = wave * 4 + i;
        int row = j * 8 + srow;
        int sg = sseg ^ (row & 7);
        gload16((const bf16_t*)Bw + (size_t)(n0 + row) * K + k0 + sg * 8, &Bs[j * 512]);
      }
    } else {
      // fp32 B: 1024 chunks of 8 elems; 256 threads x 4 reps
#pragma unroll
      for (int rep = 0; rep < 4; rep++) {
        int l = tid + rep * 256;
        int row = l >> 3, sg = l & 7;
        const float* gb = (const float*)Bw + (size_t)(n0 + row) * K + k0 + sg * 8;
        float4 f0 = *(const float4*)gb;
        float4 f1 = *(const float4*)(gb + 4);
        bf16x8 v;
        v[0] = (bf16_t)f0.x; v[1] = (bf16_t)f0.y; v[2] = (bf16_t)f0.z; v[3] = (bf16_t)f0.w;
        v[4] = (bf16_t)f1.x; v[5] = (bf16_t)f1.y; v[6] = (bf16_t)f1.z; v[7] = (bf16_t)f1.w;
        *(bf16x8*)&Bs[row * 64 + (sg ^ (row & 7)) * 8] = v;
      }
    }
    __syncthreads();
    // ---- fragments + MFMA: 2 x (K=32) sub-steps, 32 MFMA per barrier pair
#pragma unroll
    for (int kk = 0; kk < 2; kk++) {
      int ck = (ksel + 4 * kk) ^ (lane & 7);    // swizzled chunk (row&7 == lane&7 for frag rows)
      bf16x8 aF[4], bF[4];
#pragma unroll
      for (int mi = 0; mi < 4; mi++)
        aF[mi] = *(const bf16x8*)&As[(wr * 64 + mi * 16 + m16) * 64 + ck * 8];
#pragma unroll
      for (int ni = 0; ni < 4; ni++)
        bF[ni] = *(const bf16x8*)&Bs[(wc * 64 + ni * 16 + m16) * 64 + ck * 8];
#pragma unroll
      for (int mi = 0; mi < 4; mi++)
#pragma unroll
        for (int ni = 0; ni < 4; ni++)
          acc[mi][ni] = __builtin_amdgcn_mfma_f32_16x16x32_bf16(aF[mi], bF[ni], acc[mi][ni], 0, 0, 0);
    }
    __syncthreads();
  }

#pragma unroll
  for (int mi = 0; mi < 4; mi++)
#pragma unroll
    for (int ni = 0; ni < 4; ni++)
#pragma unroll
      for (int r = 0; r < 4; r++) {
        int row = m0 + wr * 64 + mi * 16 + ksel * 4 + r;
        int col = n0 + wc * 64 + ni * 16 + m16;
        size_t off = (size_t)row * N + col;
        float v = acc[mi][ni][r];
        if (mode == 0) {
          Cf[off] = v;
        } else if (mode == 1) {
          float o = v + res[off];
          Cf[off] = o;
          Cb[off] = (bf16_t)o;
        } else {
          Cf[off] = v;            // fp32 logits
        }
      }
}

// ---------------------------------------------------------------------------
// Depthwise causal conv1d (K=4) + bias + SiLU. x_in = xz[:, 0:1536] (f32).
// ---------------------------------------------------------------------------
__global__ __launch_bounds__(256) void conv_silu(const float* __restrict__ xz,
                                                 const bf16_t* __restrict__ cw,
                                                 const bf16_t* __restrict__ cb,
                                                 bf16_t* __restrict__ xc) {
  int idx = blockIdx.x * 256 + threadIdx.x;   // NROWS*D_INNER
  if (idx >= NROWS * D_INNER) return;
  int d = idx % D_INNER;
  int row = idx / D_INNER;
  int l = row % LSEQ;
  int base = row - l;                         // start row of this batch
  float s = (float)cb[d];
#pragma unroll
  for (int k = 0; k < 4; k++) {
    int ll = l - 3 + k;
    if (ll >= 0) s += (float)cw[d * 4 + k] * xz[(size_t)(base + ll) * (2 * D_INNER) + d];
  }
  float sil = s / (1.f + __expf(-s));
  xc[idx] = (bf16_t)sil;
}

// ---------------------------------------------------------------------------
// x_proj: x_dbl(2048,80) = xc(2048,1536) @ W(80,1536)^T. One block per row.
// ---------------------------------------------------------------------------
__device__ inline float bflo(unsigned int u) { return __uint_as_float(u << 16); }
__device__ inline float bfhi(unsigned int u) { return __uint_as_float(u & 0xffff0000u); }

__global__ __launch_bounds__(128) void xproj_kernel(const bf16_t* __restrict__ xc,
                                                    const bf16_t* __restrict__ W,
                                                    float* __restrict__ xdbl) {
  __shared__ unsigned int srow[D_INNER / 2];
  int row = blockIdx.x;
  const unsigned int* src = (const unsigned int*)(xc + (size_t)row * D_INNER);
  for (int i = threadIdx.x; i < D_INNER / 2; i += 128) srow[i] = src[i];
  __syncthreads();
  int j = threadIdx.x;
  if (j < DT_RANK + 2 * D_STATE) {
    const unsigned int* wr = (const unsigned int*)(W + (size_t)j * D_INNER);
    float s = 0.f;
    for (int i = 0; i < D_INNER / 2; i++) {
      unsigned int a = srow[i], w = wr[i];
      s = fmaf(bflo(a), bflo(w), s);
      s = fmaf(bfhi(a), bfhi(w), s);
    }
    xdbl[(size_t)row * 80 + j] = s;
  }
}

// ---------------------------------------------------------------------------
// dt_proj + softplus: dt(2048,1536) = softplus(x_dbl[:, :48] @ W(1536,48)^T + b)
// ---------------------------------------------------------------------------
__global__ __launch_bounds__(256) void dtproj_kernel(const float* __restrict__ xdbl,
                                                     const bf16_t* __restrict__ W,
                                                     const bf16_t* __restrict__ bias,
                                                     float* __restrict__ dt) {
  int idx = blockIdx.x * 256 + threadIdx.x;  // NROWS*D_INNER
  if (idx >= NROWS * D_INNER) return;
  int d = idx % D_INNER;
  int row = idx / D_INNER;
  const bf16_t* wr = W + (size_t)d * DT_RANK;
  const float* xr = xdbl + (size_t)row * 80;
  float s = (float)bias[d];
#pragma unroll 8
  for (int r = 0; r < DT_RANK; r++) s = fmaf(xr[r], (float)wr[r], s);
  float sp = (s > 20.f) ? s : log1pf(__expf(s));
  dt[idx] = sp;
}

// ---------------------------------------------------------------------------
// Selective scan fused with D-skip and SiLU(z) gating -> yg (bf16).
// One lane per (b,d,n); 16-lane reduce over n via DPP (VALU-only).
// Depth-8 software pipeline on the per-row loads; ring buffers are
// compile-time indexed. Over-reads land in later scratch regions (valid).
// ---------------------------------------------------------------------------
template <int CTRL>
__device__ __forceinline__ float dpp_perm(float x) {
  return __int_as_float(
      __builtin_amdgcn_update_dpp(0, __float_as_int(x), CTRL, 0xf, 0xf, false));
}

__global__ __launch_bounds__(64) void scan_kernel(const float* __restrict__ dt,
                                                  const bf16_t* __restrict__ xc,
                                                  const float* __restrict__ xdbl,
                                                  const float* __restrict__ xz,
                                                  const bf16_t* __restrict__ A_log,
                                                  const bf16_t* __restrict__ Dp,
                                                  bf16_t* __restrict__ yg) {
  int tid = threadIdx.x;
  int chan = blockIdx.x * 4 + (tid >> 4);    // 0..3071
  int b = chan / D_INNER, d = chan - (chan / D_INNER) * D_INNER;
  int n = tid & 15;
  float Adn = -__expf((float)A_log[d * D_STATE + n]);
  float Dd = (float)Dp[d];
  float h = 0.f;
  size_t baseRow = (size_t)b * LSEQ;

  float pd[8], pu[8], pB[8], pC[8], pz[8];
#pragma unroll
  for (int q = 0; q < 8; q++) {
    size_t r = baseRow + q;
    pd[q] = dt[r * D_INNER + d];
    pu[q] = (float)xc[r * D_INNER + d];
    pB[q] = xdbl[r * 80 + DT_RANK + n];
    pC[q] = xdbl[r * 80 + DT_RANK + D_STATE + n];
    pz[q] = (n == 0) ? xz[r * (2 * D_INNER) + D_INNER + d] : 0.f;
  }

  for (int l0 = 0; l0 < LSEQ; l0 += 8) {
#pragma unroll
    for (int q = 0; q < 8; q++) {
      size_t r = baseRow + l0 + q;
      float dtv = pd[q], uv = pu[q], Bv = pB[q], Cv = pC[q], zv = pz[q];
      size_t rp = r + 8;
      pd[q] = dt[rp * D_INNER + d];
      pu[q] = (float)xc[rp * D_INNER + d];
      pB[q] = xdbl[rp * 80 + DT_RANK + n];
      pC[q] = xdbl[rp * 80 + DT_RANK + D_STATE + n];
      pz[q] = (n == 0) ? xz[rp * (2 * D_INNER) + D_INNER + d] : 0.f;

      float dA = __expf(dtv * Adn);
      h = fmaf(dA, h, dtv * Bv * uv);
      float p = h * Cv;
      p += dpp_perm<0xB1>(p);    // quad_perm [1,0,3,2]  (xor 1)
      p += dpp_perm<0x4E>(p);    // quad_perm [2,3,0,1]  (xor 2)
      p += dpp_perm<0x124>(p);   // row_ror:4
      p += dpp_perm<0x128>(p);   // row_ror:8
      if (n == 0) {
        float sil = zv / (1.f + __expf(-zv));
        float y = (p + Dd * uv) * sil;
        yg[r * D_INNER + d] = (bf16_t)y;
      }
    }
  }
}

// ---------------------------------------------------------------------------
// LayerNorm over 768, bf16 out (logits A-operand).
// ---------------------------------------------------------------------------
__global__ __launch_bounds__(256) void ln_kernel(const float* __restrict__ h,
                                                 const bf16_t* __restrict__ w,
                                                 const bf16_t* __restrict__ b,
                                                 bf16_t* __restrict__ out) {
  __shared__ float s1[4], s2[4];
  int row = blockIdx.x;
  int tid = threadIdx.x, lane = tid & 63, wave = tid >> 6;
  const float* hr = h + (size_t)row * D_MODEL;
  float a = 0.f, a2 = 0.f;
  for (int i = tid; i < D_MODEL; i += 256) {
    float v = hr[i];
    a += v; a2 += v * v;
  }
#pragma unroll
  for (int m = 32; m >= 1; m >>= 1) {
    a += __shfl_xor(a, m, 64);
    a2 += __shfl_xor(a2, m, 64);
  }
  if (lane == 0) { s1[wave] = a; s2[wave] = a2; }
  __syncthreads();
  float sum = s1[0] + s1[1] + s1[2] + s1[3];
  float sum2 = s2[0] + s2[1] + s2[2] + s2[3];
  float mu = sum / D_MODEL;
  float var = sum2 / D_MODEL - mu * mu;
  float inv = rsqrtf(var + 1e-5f);
  for (int i = tid; i < D_MODEL; i += 256)
    out[(size_t)row * D_MODEL + i] = (bf16_t)((hr[i] - mu) * inv * (float)w[i] + (float)b[i]);
}

// ---------------------------------------------------------------------------
extern "C" void kernel_launch(void* const* d_in, const int* in_sizes, int n_in,
                              void* d_out, int out_size, void* d_ws, size_t ws_size,
                              hipStream_t stream) {
  const int* x = (const int*)d_in[0];
  const void* emb = d_in[1];
  float* out = (float*)d_out;                    // OUTPUT IS FP32 (reference dtype)

  // --- scratch inside d_out (dead before the final logits GEMM writes it) ---
  char* ob = (char*)d_out;
  float* h = (float*)(ob + 0);                   //  6,291,456 B
  bf16_t* hb = (bf16_t*)(ob + 6291456);          //  3,145,728 B
  float* xz = (float*)(ob + 9437184);            // 25,165,824 B
  bf16_t* xc = (bf16_t*)(ob + 34603008);         //  6,291,456 B
  float* xdbl = (float*)(ob + 40894464);         //    655,360 B
  float* dt = (float*)(ob + 41549824);           // 12,582,912 B
  bf16_t* yg = (bf16_t*)(ob + 54132736);         //  6,291,456 B
  bf16_t* wk = (bf16_t*)(ob + 60424192);         // 15,086,592 B canonical bf16 weights
  // --- d_ws: data that must survive the logits GEMM + dtype flag ---
  bf16_t* lno = (bf16_t*)d_ws;                   //  3,145,728 B
  int* flag = (int*)((char*)d_ws + 3145728);
  bf16_t* embb = (bf16_t*)((char*)d_ws + 3145744); // 49,152,000 B (optional)
  bool bigws = ws_size >= (size_t)3145744 + 49152000u;

  // canonical weight layout (element offsets into wk)
  bf16_t* c_inw  = wk + 0;          // 2*3072*768 = 4,718,592
  bf16_t* c_cw   = wk + 4718592;    // 12,288
  bf16_t* c_cb   = wk + 4730880;    // 3,072
  bf16_t* c_xpw  = wk + 4733952;    // 245,760
  bf16_t* c_dtw  = wk + 4979712;    // 147,456
  bf16_t* c_dtb  = wk + 5127168;    // 3,072
  bf16_t* c_alog = wk + 5130240;    // 49,152
  bf16_t* c_dp   = wk + 5179392;    // 3,072
  bf16_t* c_outw = wk + 5182464;    // 2,359,296
  bf16_t* c_lnw  = wk + 7541760;    // 768
  bf16_t* c_lnb  = wk + 7542528;    // 768

  detect_kernel<<<1, 64, 0, stream>>>((const unsigned int*)d_in[11], flag);

  CvtSrcs srcs;
  for (int k = 0; k < 11; k++) srcs.p[k] = d_in[k + 2];
  const int cvt_total = 7543296;
  cvt_all<<<(cvt_total + 255) / 256, 256, 0, stream>>>(srcs, wk, cvt_total, flag);

  if (bigws)
    cvt_emb<<<(32000 * 768 / 8 + 255) / 256, 256, 0, stream>>>(emb, embb, flag);

  embed_kernel<<<(NROWS * D_MODEL + 255) / 256, 256, 0, stream>>>(x, emb, h, hb, flag);

  for (int i = 0; i < 2; i++) {
    gemm_bt<<<dim3(3072 / 128, NROWS / 128), 256, 0, stream>>>(
        hb, c_inw + (size_t)i * 2 * D_INNER * D_MODEL, NROWS, 2 * D_INNER, D_MODEL,
        0, xz, nullptr, nullptr, nullptr, 0);
    conv_silu<<<(NROWS * D_INNER + 255) / 256, 256, 0, stream>>>(
        xz, c_cw + (size_t)i * D_INNER * 4, c_cb + (size_t)i * D_INNER, xc);
    xproj_kernel<<<NROWS, 128, 0, stream>>>(xc, c_xpw + (size_t)i * 80 * D_INNER, xdbl);
    dtproj_kernel<<<(NROWS * D_INNER + 255) / 256, 256, 0, stream>>>(
        xdbl, c_dtw + (size_t)i * D_INNER * DT_RANK, c_dtb + (size_t)i * D_INNER, dt);
    scan_kernel<<<(2 * D_INNER) / 4, 64, 0, stream>>>(
        dt, xc, xdbl, xz, c_alog + (size_t)i * D_INNER * D_STATE, c_dp + (size_t)i * D_INNER, yg);
    gemm_bt<<<dim3(D_MODEL / 128, NROWS / 128), 256, 0, stream>>>(
        yg, c_outw + (size_t)i * D_MODEL * D_INNER, NROWS, D_MODEL, D_INNER,
        1, h, hb, h, nullptr, 0);
  }

  ln_kernel<<<NROWS, 256, 0, stream>>>(h, c_lnw, c_lnb, lno);

  // logits (fp32) = lno @ emb^T. swapgrid=1: B-panel sharers dispatch-adjacent.
  if (bigws)
    gemm_bt<<<dim3(NROWS / 128, 32000 / 128), 256, 0, stream>>>(
        lno, embb, NROWS, 32000, D_MODEL, 2, out, nullptr, nullptr, nullptr, 1);
  else
    gemm_bt<<<dim3(NROWS / 128, 32000 / 128), 256, 0, stream>>>(
        lno, emb, NROWS, 32000, D_MODEL, 2, out, nullptr, nullptr, flag, 1);
}

// Round 3
// 1007.767 us; speedup vs baseline: 1.5421x; 1.3084x over previous
//
#include <hip/hip_runtime.h>
#include <hip/hip_bf16.h>

typedef __bf16 bf16_t;
typedef __bf16 bf16x8 __attribute__((ext_vector_type(8)));
typedef float floatx4 __attribute__((ext_vector_type(4)));

#define D_MODEL 768
#define D_INNER 1536
#define D_STATE 16
#define DT_RANK 48
#define NROWS 2048   /* B*L */
#define LSEQ 1024
#define SCAN_C 32            /* chunks per sequence */
#define SCAN_RPC 32          /* rows per chunk = LSEQ/SCAN_C */
#define SCAN_NDG 24          /* d-groups of 64 = D_INNER/64 */
#define SCAN_STRIDE 24576    /* D_INNER*D_STATE floats per (b,chunk) */

// ---------------------------------------------------------------------------
// Input dtype detection: ln_w is all-ones. fp32 -> first word 0x3F800000,
// bf16 -> 0x3F803F80. flag: 1 = inputs are bf16, 0 = inputs are fp32.
// Measured: flag==0 on this harness (inputs fp32).
// ---------------------------------------------------------------------------
__global__ void detect_kernel(const unsigned int* __restrict__ lnw, int* __restrict__ flag) {
  if (threadIdx.x == 0 && blockIdx.x == 0)
    *flag = (lnw[0] == 0x3F800000u) ? 0 : 1;
}

// ---------------------------------------------------------------------------
// Merged canonicalizer: all 11 weight tensors -> contiguous bf16 wk buffer.
// ---------------------------------------------------------------------------
struct CvtSrcs { const void* p[11]; };

__global__ __launch_bounds__(256) void cvt_all(CvtSrcs sp, bf16_t* __restrict__ wk,
                                               int total, const int* __restrict__ flagp) {
  int i = blockIdx.x * 256 + threadIdx.x;
  if (i >= total) return;
  const int off[12] = {0, 4718592, 4730880, 4733952, 4979712, 5127168, 5130240,
                       5179392, 5182464, 7541760, 7542528, 7543296};
  const void* src = sp.p[0];
  int base = 0;
#pragma unroll
  for (int k = 1; k <= 10; k++) {
    if (i >= off[k]) { src = sp.p[k]; base = off[k]; }
  }
  int j = i - base;
  float v = (*flagp) ? (float)((const bf16_t*)src)[j] : ((const float*)src)[j];
  wk[i] = (bf16_t)v;
}

// ---------------------------------------------------------------------------
// Optional: full embedding table -> bf16 (only if d_ws is big enough).
// ---------------------------------------------------------------------------
__global__ __launch_bounds__(256) void cvt_emb(const void* __restrict__ src,
                                               bf16_t* __restrict__ dst,
                                               const int* __restrict__ flagp) {
  int i = blockIdx.x * 256 + threadIdx.x;      // chunk of 8 elements
  const int nchunk = 32000 * 768 / 8;
  if (i >= nchunk) return;
  if (*flagp) {
    ((uint4*)dst)[i] = ((const uint4*)src)[i];
  } else {
    const float4* s = (const float4*)src + (size_t)i * 2;
    float4 f0 = s[0], f1 = s[1];
    bf16x8 v;
    v[0] = (bf16_t)f0.x; v[1] = (bf16_t)f0.y; v[2] = (bf16_t)f0.z; v[3] = (bf16_t)f0.w;
    v[4] = (bf16_t)f1.x; v[5] = (bf16_t)f1.y; v[6] = (bf16_t)f1.z; v[7] = (bf16_t)f1.w;
    *(bf16x8*)(dst + (size_t)i * 8) = v;
  }
}

// ---------------------------------------------------------------------------
// Embedding gather: h (f32 residual stream) and hb (bf16 GEMM A-operand).
// ---------------------------------------------------------------------------
__global__ __launch_bounds__(256) void embed_kernel(const int* __restrict__ x,
                                                    const void* __restrict__ emb,
                                                    float* __restrict__ h,
                                                    bf16_t* __restrict__ hb,
                                                    const int* __restrict__ flagp) {
  int isbf = *flagp;
  int idx = blockIdx.x * 256 + threadIdx.x;           // 2048*768
  if (idx >= NROWS * D_MODEL) return;
  int row = idx / D_MODEL, c = idx - row * D_MODEL;
  size_t o = (size_t)x[row] * D_MODEL + c;
  float v = isbf ? (float)((const bf16_t*)emb)[o] : ((const float*)emb)[o];
  h[idx] = v;
  hb[idx] = (bf16_t)v;
}

// ---------------------------------------------------------------------------
// MFMA GEMM: C(M,N) = A(M,K) * Bw(N,K)^T. A always bf16 (16B-aligned rows).
// K must be a multiple of 64. BK=64, linear LDS, global_load_lds dwordx4
// with XOR chunk swizzle (source+read sides; rule 21).
// mode 0: Cf = acc; mode 1: v=acc+res -> Cf,Cb; mode 2: Cf = acc (logits fp32)
// swapgrid: m-block index fastest -> B-panel sharers dispatch-adjacent.
// ---------------------------------------------------------------------------
typedef __attribute__((address_space(3))) void lds_void_t;
typedef __attribute__((address_space(1))) void glb_void_t;

__device__ __forceinline__ void gload16(const void* g, void* l) {
  __builtin_amdgcn_global_load_lds((const glb_void_t*)(unsigned long long)g,
                                   (lds_void_t*)(unsigned long long)l, 16, 0, 0);
}

__global__ __launch_bounds__(256) void gemm_bt(const bf16_t* __restrict__ A,
                                               const void* __restrict__ Bw,
                                               int M, int N, int K, int mode,
                                               float* __restrict__ Cf,
                                               bf16_t* __restrict__ Cb,
                                               const float* __restrict__ res,
                                               const int* __restrict__ flagp,
                                               int swapgrid) {
  __shared__ __align__(16) bf16_t As[128 * 64];
  __shared__ __align__(16) bf16_t Bs[128 * 64];
  int bNative = flagp ? (*flagp == 0) : 0;      // 1 -> Bw is fp32
  int tid = threadIdx.x;
  int nb = swapgrid ? blockIdx.y : blockIdx.x;
  int mb = swapgrid ? blockIdx.x : blockIdx.y;
  int m0 = mb * 128, n0 = nb * 128;
  int wave = tid >> 6, lane = tid & 63;
  int wr = wave >> 1, wc = wave & 1;
  int m16 = lane & 15, ksel = lane >> 4;
  int srow = lane >> 3;                         // 0..7 within an 8-row slab
  int sseg = lane & 7;

  floatx4 acc[4][4];
#pragma unroll
  for (int i = 0; i < 4; i++)
#pragma unroll
    for (int j = 0; j < 4; j++) acc[i][j] = (floatx4){0.f, 0.f, 0.f, 0.f};

  for (int k0 = 0; k0 < K; k0 += 64) {
#pragma unroll
    for (int i = 0; i < 4; i++) {
      int j = wave * 4 + i;
      int row = j * 8 + srow;
      int sg = sseg ^ (row & 7);
      gload16(A + (size_t)(m0 + row) * K + k0 + sg * 8, &As[j * 512]);
    }
    if (!bNative) {
#pragma unroll
      for (int i = 0; i < 4; i++) {
        int j = wave * 4 + i;
        int row = j * 8 + srow;
        int sg = sseg ^ (row & 7);
        gload16((const bf16_t*)Bw + (size_t)(n0 + row) * K + k0 + sg * 8, &Bs[j * 512]);
      }
    } else {
#pragma unroll
      for (int rep = 0; rep < 4; rep++) {
        int l = tid + rep * 256;
        int row = l >> 3, sg = l & 7;
        const float* gb = (const float*)Bw + (size_t)(n0 + row) * K + k0 + sg * 8;
        float4 f0 = *(const float4*)gb;
        float4 f1 = *(const float4*)(gb + 4);
        bf16x8 v;
        v[0] = (bf16_t)f0.x; v[1] = (bf16_t)f0.y; v[2] = (bf16_t)f0.z; v[3] = (bf16_t)f0.w;
        v[4] = (bf16_t)f1.x; v[5] = (bf16_t)f1.y; v[6] = (bf16_t)f1.z; v[7] = (bf16_t)f1.w;
        *(bf16x8*)&Bs[row * 64 + (sg ^ (row & 7)) * 8] = v;
      }
    }
    __syncthreads();
#pragma unroll
    for (int kk = 0; kk < 2; kk++) {
      int ck = (ksel + 4 * kk) ^ (lane & 7);
      bf16x8 aF[4], bF[4];
#pragma unroll
      for (int mi = 0; mi < 4; mi++)
        aF[mi] = *(const bf16x8*)&As[(wr * 64 + mi * 16 + m16) * 64 + ck * 8];
#pragma unroll
      for (int ni = 0; ni < 4; ni++)
        bF[ni] = *(const bf16x8*)&Bs[(wc * 64 + ni * 16 + m16) * 64 + ck * 8];
#pragma unroll
      for (int mi = 0; mi < 4; mi++)
#pragma unroll
        for (int ni = 0; ni < 4; ni++)
          acc[mi][ni] = __builtin_amdgcn_mfma_f32_16x16x32_bf16(aF[mi], bF[ni], acc[mi][ni], 0, 0, 0);
    }
    __syncthreads();
  }

#pragma unroll
  for (int mi = 0; mi < 4; mi++)
#pragma unroll
    for (int ni = 0; ni < 4; ni++)
#pragma unroll
      for (int r = 0; r < 4; r++) {
        int row = m0 + wr * 64 + mi * 16 + ksel * 4 + r;
        int col = n0 + wc * 64 + ni * 16 + m16;
        size_t off = (size_t)row * N + col;
        float v = acc[mi][ni][r];
        if (mode == 0) {
          Cf[off] = v;
        } else if (mode == 1) {
          float o = v + res[off];
          Cf[off] = o;
          Cb[off] = (bf16_t)o;
        } else {
          Cf[off] = v;
        }
      }
}

// ---------------------------------------------------------------------------
// Depthwise causal conv1d (K=4) + bias + SiLU. x_in = xz[:, 0:1536] (f32).
// ---------------------------------------------------------------------------
__global__ __launch_bounds__(256) void conv_silu(const float* __restrict__ xz,
                                                 const bf16_t* __restrict__ cw,
                                                 const bf16_t* __restrict__ cb,
                                                 bf16_t* __restrict__ xc) {
  int idx = blockIdx.x * 256 + threadIdx.x;   // NROWS*D_INNER
  if (idx >= NROWS * D_INNER) return;
  int d = idx % D_INNER;
  int row = idx / D_INNER;
  int l = row % LSEQ;
  int base = row - l;                         // start row of this batch
  float s = (float)cb[d];
#pragma unroll
  for (int k = 0; k < 4; k++) {
    int ll = l - 3 + k;
    if (ll >= 0) s += (float)cw[d * 4 + k] * xz[(size_t)(base + ll) * (2 * D_INNER) + d];
  }
  float sil = s / (1.f + __expf(-s));
  xc[idx] = (bf16_t)sil;
}

// ---------------------------------------------------------------------------
// x_proj: x_dbl(2048,80) = xc(2048,1536) @ W(80,1536)^T. One block per row.
// ---------------------------------------------------------------------------
__device__ inline float bflo(unsigned int u) { return __uint_as_float(u << 16); }
__device__ inline float bfhi(unsigned int u) { return __uint_as_float(u & 0xffff0000u); }

__global__ __launch_bounds__(128) void xproj_kernel(const bf16_t* __restrict__ xc,
                                                    const bf16_t* __restrict__ W,
                                                    float* __restrict__ xdbl) {
  __shared__ unsigned int srow[D_INNER / 2];
  int row = blockIdx.x;
  const unsigned int* src = (const unsigned int*)(xc + (size_t)row * D_INNER);
  for (int i = threadIdx.x; i < D_INNER / 2; i += 128) srow[i] = src[i];
  __syncthreads();
  int j = threadIdx.x;
  if (j < DT_RANK + 2 * D_STATE) {
    const unsigned int* wr = (const unsigned int*)(W + (size_t)j * D_INNER);
    float s = 0.f;
    for (int i = 0; i < D_INNER / 2; i++) {
      unsigned int a = srow[i], w = wr[i];
      s = fmaf(bflo(a), bflo(w), s);
      s = fmaf(bfhi(a), bfhi(w), s);
    }
    xdbl[(size_t)row * 80 + j] = s;
  }
}

// ---------------------------------------------------------------------------
// dt_proj + softplus: dt(2048,1536) = softplus(x_dbl[:, :48] @ W(1536,48)^T + b)
// ---------------------------------------------------------------------------
__global__ __launch_bounds__(256) void dtproj_kernel(const float* __restrict__ xdbl,
                                                     const bf16_t* __restrict__ W,
                                                     const bf16_t* __restrict__ bias,
                                                     float* __restrict__ dt) {
  int idx = blockIdx.x * 256 + threadIdx.x;  // NROWS*D_INNER
  if (idx >= NROWS * D_INNER) return;
  int d = idx % D_INNER;
  int row = idx / D_INNER;
  const bf16_t* wr = W + (size_t)d * DT_RANK;
  const float* xr = xdbl + (size_t)row * 80;
  float s = (float)bias[d];
#pragma unroll 8
  for (int r = 0; r < DT_RANK; r++) s = fmaf(xr[r], (float)wr[r], s);
  float sp = (s > 20.f) ? s : log1pf(__expf(s));
  dt[idx] = sp;
}

// ---------------------------------------------------------------------------
// Chunked selective scan (3 phases). Decomposition: lane = channel d (64
// consecutive per wave -> all per-row streams fully coalesced), the 16
// n-states live in REGISTERS (no cross-lane reduce), L split into 32 chunks
// of 32 rows (h <- dA*h + dBu is linear in h => chunk-decomposable).
// Phase1: per chunk, P = prod(dA), F = h(end | h_start=0)   per (d,n)
// Phase2: h_in(c) = P(c-1)*h_in(c-1) + F(c-1)               (serial, tiny)
// Phase3: re-scan chunk seeded with h_in; y = sum_n h*C + D*u, SiLU(z) gate.
// P/F/Hin layout: [(b*32+c)][d][n] -> lane stores/loads 16 consecutive f32.
// Over-reads by the depth-1 prefetch at chunk end land in adjacent scratch
// regions of d_out (valid memory) and are discarded.
// ---------------------------------------------------------------------------
__global__ __launch_bounds__(64) void scan_p1(const float* __restrict__ dt_,
                                              const bf16_t* __restrict__ xc,
                                              const float* __restrict__ xdbl,
                                              const bf16_t* __restrict__ A_log,
                                              float* __restrict__ P,
                                              float* __restrict__ F) {
  int wg = blockIdx.x;                 // 0..1535
  int dgrp = wg % SCAN_NDG, c2 = wg / SCAN_NDG;   // c2 = b*32+c, 0..63
  int b = c2 >> 5, c = c2 & 31;
  int d = dgrp * 64 + threadIdx.x;
  int r0 = b * LSEQ + c * SCAN_RPC;

  float Adn[16];
  {
    bf16x8 a0 = *(const bf16x8*)(A_log + (size_t)d * 16);
    bf16x8 a1 = *(const bf16x8*)(A_log + (size_t)d * 16 + 8);
#pragma unroll
    for (int n = 0; n < 8; n++) { Adn[n] = -__expf((float)a0[n]); Adn[n + 8] = -__expf((float)a1[n]); }
  }
  float h[16], p[16];
#pragma unroll
  for (int n = 0; n < 16; n++) { h[n] = 0.f; p[n] = 1.f; }

  float dtv = dt_[(size_t)r0 * D_INNER + d];
  float uv = (float)xc[(size_t)r0 * D_INNER + d];
  float Bv[16];
  {
    const float4* bp = (const float4*)(xdbl + (size_t)r0 * 80 + DT_RANK);
#pragma unroll
    for (int q = 0; q < 4; q++) *(float4*)&Bv[q * 4] = bp[q];
  }

  for (int i = 0; i < SCAN_RPC; i++) {
    int rn = r0 + i + 1;               // depth-1 prefetch (over-read OK)
    float dtn = dt_[(size_t)rn * D_INNER + d];
    float un = (float)xc[(size_t)rn * D_INNER + d];
    float Bn[16];
    {
      const float4* bp = (const float4*)(xdbl + (size_t)rn * 80 + DT_RANK);
#pragma unroll
      for (int q = 0; q < 4; q++) *(float4*)&Bn[q * 4] = bp[q];
    }
    float dtu = dtv * uv;
#pragma unroll
    for (int n = 0; n < 16; n++) {
      float dA = __expf(dtv * Adn[n]);
      h[n] = fmaf(dA, h[n], dtu * Bv[n]);
      p[n] *= dA;
    }
    dtv = dtn; uv = un;
#pragma unroll
    for (int n = 0; n < 16; n++) Bv[n] = Bn[n];
  }

  size_t o = (size_t)c2 * SCAN_STRIDE + (size_t)d * 16;
#pragma unroll
  for (int q = 0; q < 4; q++) {
    *(float4*)(P + o + q * 4) = *(float4*)&p[q * 4];
    *(float4*)(F + o + q * 4) = *(float4*)&h[q * 4];
  }
}

__global__ __launch_bounds__(256) void scan_p2(const float* __restrict__ P,
                                               const float* __restrict__ F,
                                               float* __restrict__ Hin) {
  int gid = blockIdx.x * 256 + threadIdx.x;   // < 49152 = 2*24576
  if (gid >= 2 * SCAN_STRIDE) return;
  int b = gid / SCAN_STRIDE, j = gid - b * SCAN_STRIDE;
  float pP[SCAN_C], pF[SCAN_C];
#pragma unroll
  for (int c = 0; c < SCAN_C; c++) {
    size_t o = (size_t)(b * SCAN_C + c) * SCAN_STRIDE + j;
    pP[c] = P[o]; pF[c] = F[o];
  }
  float h = 0.f;
#pragma unroll
  for (int c = 0; c < SCAN_C; c++) {
    size_t o = (size_t)(b * SCAN_C + c) * SCAN_STRIDE + j;
    Hin[o] = h;
    h = fmaf(pP[c], h, pF[c]);
  }
}

__global__ __launch_bounds__(64) void scan_p3(const float* __restrict__ dt_,
                                              const bf16_t* __restrict__ xc,
                                              const float* __restrict__ xdbl,
                                              const float* __restrict__ xz,
                                              const bf16_t* __restrict__ A_log,
                                              const bf16_t* __restrict__ Dp,
                                              const float* __restrict__ Hin,
                                              bf16_t* __restrict__ yg) {
  int wg = blockIdx.x;
  int dgrp = wg % SCAN_NDG, c2 = wg / SCAN_NDG;
  int b = c2 >> 5, c = c2 & 31;
  int d = dgrp * 64 + threadIdx.x;
  int r0 = b * LSEQ + c * SCAN_RPC;

  float Adn[16];
  {
    bf16x8 a0 = *(const bf16x8*)(A_log + (size_t)d * 16);
    bf16x8 a1 = *(const bf16x8*)(A_log + (size_t)d * 16 + 8);
#pragma unroll
    for (int n = 0; n < 8; n++) { Adn[n] = -__expf((float)a0[n]); Adn[n + 8] = -__expf((float)a1[n]); }
  }
  float Dd = (float)Dp[d];
  float h[16];
  {
    size_t o = (size_t)c2 * SCAN_STRIDE + (size_t)d * 16;
#pragma unroll
    for (int q = 0; q < 4; q++) *(float4*)&h[q * 4] = *(const float4*)(Hin + o + q * 4);
  }

  float dtv = dt_[(size_t)r0 * D_INNER + d];
  float uv = (float)xc[(size_t)r0 * D_INNER + d];
  float zv = xz[(size_t)r0 * (2 * D_INNER) + D_INNER + d];
  float Bv[16], Cv[16];
  {
    const float4* bp = (const float4*)(xdbl + (size_t)r0 * 80 + DT_RANK);
#pragma unroll
    for (int q = 0; q < 4; q++) *(float4*)&Bv[q * 4] = bp[q];
#pragma unroll
    for (int q = 0; q < 4; q++) *(float4*)&Cv[q * 4] = bp[q + 4];
  }

  for (int i = 0; i < SCAN_RPC; i++) {
    int r = r0 + i;
    int rn = r + 1;                    // depth-1 prefetch (over-read OK)
    float dtn = dt_[(size_t)rn * D_INNER + d];
    float un = (float)xc[(size_t)rn * D_INNER + d];
    float zn = xz[(size_t)rn * (2 * D_INNER) + D_INNER + d];
    float Bn[16], Cn[16];
    {
      const float4* bp = (const float4*)(xdbl + (size_t)rn * 80 + DT_RANK);
#pragma unroll
      for (int q = 0; q < 4; q++) *(float4*)&Bn[q * 4] = bp[q];
#pragma unroll
      for (int q = 0; q < 4; q++) *(float4*)&Cn[q * 4] = bp[q + 4];
    }
    float dtu = dtv * uv;
    float y = 0.f;
#pragma unroll
    for (int n = 0; n < 16; n++) {
      float dA = __expf(dtv * Adn[n]);
      h[n] = fmaf(dA, h[n], dtu * Bv[n]);
      y = fmaf(h[n], Cv[n], y);
    }
    float sil = zv / (1.f + __expf(-zv));
    yg[(size_t)r * D_INNER + d] = (bf16_t)((y + Dd * uv) * sil);
    dtv = dtn; uv = un; zv = zn;
#pragma unroll
    for (int n = 0; n < 16; n++) { Bv[n] = Bn[n]; Cv[n] = Cn[n]; }
  }
}

// ---------------------------------------------------------------------------
// LayerNorm over 768, bf16 out (logits A-operand).
// ---------------------------------------------------------------------------
__global__ __launch_bounds__(256) void ln_kernel(const float* __restrict__ h,
                                                 const bf16_t* __restrict__ w,
                                                 const bf16_t* __restrict__ b,
                                                 bf16_t* __restrict__ out) {
  __shared__ float s1[4], s2[4];
  int row = blockIdx.x;
  int tid = threadIdx.x, lane = tid & 63, wave = tid >> 6;
  const float* hr = h + (size_t)row * D_MODEL;
  float a = 0.f, a2 = 0.f;
  for (int i = tid; i < D_MODEL; i += 256) {
    float v = hr[i];
    a += v; a2 += v * v;
  }
#pragma unroll
  for (int m = 32; m >= 1; m >>= 1) {
    a += __shfl_xor(a, m, 64);
    a2 += __shfl_xor(a2, m, 64);
  }
  if (lane == 0) { s1[wave] = a; s2[wave] = a2; }
  __syncthreads();
  float sum = s1[0] + s1[1] + s1[2] + s1[3];
  float sum2 = s2[0] + s2[1] + s2[2] + s2[3];
  float mu = sum / D_MODEL;
  float var = sum2 / D_MODEL - mu * mu;
  float inv = rsqrtf(var + 1e-5f);
  for (int i = tid; i < D_MODEL; i += 256)
    out[(size_t)row * D_MODEL + i] = (bf16_t)((hr[i] - mu) * inv * (float)w[i] + (float)b[i]);
}

// ---------------------------------------------------------------------------
extern "C" void kernel_launch(void* const* d_in, const int* in_sizes, int n_in,
                              void* d_out, int out_size, void* d_ws, size_t ws_size,
                              hipStream_t stream) {
  const int* x = (const int*)d_in[0];
  const void* emb = d_in[1];
  float* out = (float*)d_out;                    // OUTPUT IS FP32 (reference dtype)

  // --- scratch inside d_out (dead before the final logits GEMM writes it) ---
  char* ob = (char*)d_out;
  float* h = (float*)(ob + 0);                   //  6,291,456 B
  bf16_t* hb = (bf16_t*)(ob + 6291456);          //  3,145,728 B
  float* xz = (float*)(ob + 9437184);            // 25,165,824 B
  bf16_t* xc = (bf16_t*)(ob + 34603008);         //  6,291,456 B
  float* xdbl = (float*)(ob + 40894464);         //    655,360 B
  float* dt = (float*)(ob + 41549824);           // 12,582,912 B
  bf16_t* yg = (bf16_t*)(ob + 54132736);         //  6,291,456 B
  bf16_t* wk = (bf16_t*)(ob + 60424192);         // 15,086,592 B canonical bf16 weights
  float* scanP = (float*)(ob + 75510784);        //  6,291,456 B
  float* scanF = (float*)(ob + 81802240);        //  6,291,456 B
  float* scanH = (float*)(ob + 88093696);        //  6,291,456 B (ends 94.4 MB < 262 MB)
  // --- d_ws: data that must survive the logits GEMM + dtype flag ---
  bf16_t* lno = (bf16_t*)d_ws;                   //  3,145,728 B
  int* flag = (int*)((char*)d_ws + 3145728);
  bf16_t* embb = (bf16_t*)((char*)d_ws + 3145744); // 49,152,000 B (optional)
  bool bigws = ws_size >= (size_t)3145744 + 49152000u;

  // canonical weight layout (element offsets into wk)
  bf16_t* c_inw  = wk + 0;          // 2*3072*768 = 4,718,592
  bf16_t* c_cw   = wk + 4718592;    // 12,288
  bf16_t* c_cb   = wk + 4730880;    // 3,072
  bf16_t* c_xpw  = wk + 4733952;    // 245,760
  bf16_t* c_dtw  = wk + 4979712;    // 147,456
  bf16_t* c_dtb  = wk + 5127168;    // 3,072
  bf16_t* c_alog = wk + 5130240;    // 49,152
  bf16_t* c_dp   = wk + 5179392;    // 3,072
  bf16_t* c_outw = wk + 5182464;    // 2,359,296
  bf16_t* c_lnw  = wk + 7541760;    // 768
  bf16_t* c_lnb  = wk + 7542528;    // 768

  detect_kernel<<<1, 64, 0, stream>>>((const unsigned int*)d_in[11], flag);

  CvtSrcs srcs;
  for (int k = 0; k < 11; k++) srcs.p[k] = d_in[k + 2];
  const int cvt_total = 7543296;
  cvt_all<<<(cvt_total + 255) / 256, 256, 0, stream>>>(srcs, wk, cvt_total, flag);

  if (bigws)
    cvt_emb<<<(32000 * 768 / 8 + 255) / 256, 256, 0, stream>>>(emb, embb, flag);

  embed_kernel<<<(NROWS * D_MODEL + 255) / 256, 256, 0, stream>>>(x, emb, h, hb, flag);

  for (int i = 0; i < 2; i++) {
    gemm_bt<<<dim3(3072 / 128, NROWS / 128), 256, 0, stream>>>(
        hb, c_inw + (size_t)i * 2 * D_INNER * D_MODEL, NROWS, 2 * D_INNER, D_MODEL,
        0, xz, nullptr, nullptr, nullptr, 0);
    conv_silu<<<(NROWS * D_INNER + 255) / 256, 256, 0, stream>>>(
        xz, c_cw + (size_t)i * D_INNER * 4, c_cb + (size_t)i * D_INNER, xc);
    xproj_kernel<<<NROWS, 128, 0, stream>>>(xc, c_xpw + (size_t)i * 80 * D_INNER, xdbl);
    dtproj_kernel<<<(NROWS * D_INNER + 255) / 256, 256, 0, stream>>>(
        xdbl, c_dtw + (size_t)i * D_INNER * DT_RANK, c_dtb + (size_t)i * D_INNER, dt);
    scan_p1<<<2 * SCAN_C * SCAN_NDG, 64, 0, stream>>>(
        dt, xc, xdbl, c_alog + (size_t)i * D_INNER * D_STATE, scanP, scanF);
    scan_p2<<<(2 * SCAN_STRIDE + 255) / 256, 256, 0, stream>>>(scanP, scanF, scanH);
    scan_p3<<<2 * SCAN_C * SCAN_NDG, 64, 0, stream>>>(
        dt, xc, xdbl, xz, c_alog + (size_t)i * D_INNER * D_STATE,
        c_dp + (size_t)i * D_INNER, scanH, yg);
    gemm_bt<<<dim3(D_MODEL / 128, NROWS / 128), 256, 0, stream>>>(
        yg, c_outw + (size_t)i * D_MODEL * D_INNER, NROWS, D_MODEL, D_INNER,
        1, h, hb, h, nullptr, 0);
  }

  ln_kernel<<<NROWS, 256, 0, stream>>>(h, c_lnw, c_lnb, lno);

  // logits (fp32) = lno @ emb^T. swapgrid=1: B-panel sharers dispatch-adjacent.
  if (bigws)
    gemm_bt<<<dim3(NROWS / 128, 32000 / 128), 256, 0, stream>>>(
        lno, embb, NROWS, 32000, D_MODEL, 2, out, nullptr, nullptr, nullptr, 1);
  else
    gemm_bt<<<dim3(NROWS / 128, 32000 / 128), 256, 0, stream>>>(
        lno, emb, NROWS, 32000, D_MODEL, 2, out, nullptr, nullptr, flag, 1);
}

// Round 5
// 948.010 us; speedup vs baseline: 1.6393x; 1.0630x over previous
//
#include <hip/hip_runtime.h>
#include <hip/hip_bf16.h>

typedef __bf16 bf16_t;
typedef __bf16 bf16x8 __attribute__((ext_vector_type(8)));
typedef float floatx4 __attribute__((ext_vector_type(4)));

#define D_MODEL 768
#define D_INNER 1536
#define D_STATE 16
#define DT_RANK 48
#define NROWS 2048   /* B*L */
#define LSEQ 1024
#define SCAN_C 32            /* chunks per sequence */
#define SCAN_RPC 32          /* rows per chunk = LSEQ/SCAN_C */
#define SCAN_NDG 24          /* d-groups of 64 = D_INNER/64 */
#define SCAN_STRIDE 24576    /* D_INNER*D_STATE floats per (b,chunk) */

// ---------------------------------------------------------------------------
// Input dtype detection: ln_w is all-ones. fp32 -> first word 0x3F800000,
// bf16 -> 0x3F803F80. flag: 1 = inputs are bf16, 0 = inputs are fp32.
// Measured: flag==0 on this harness (inputs fp32).
// ---------------------------------------------------------------------------
__global__ void detect_kernel(const unsigned int* __restrict__ lnw, int* __restrict__ flag) {
  if (threadIdx.x == 0 && blockIdx.x == 0)
    *flag = (lnw[0] == 0x3F800000u) ? 0 : 1;
}

// ---------------------------------------------------------------------------
// Merged canonicalizer: all 11 weight tensors -> contiguous bf16 wk buffer.
// ---------------------------------------------------------------------------
struct CvtSrcs { const void* p[11]; };

__global__ __launch_bounds__(256) void cvt_all(CvtSrcs sp, bf16_t* __restrict__ wk,
                                               int total, const int* __restrict__ flagp) {
  int i = blockIdx.x * 256 + threadIdx.x;
  if (i >= total) return;
  const int off[12] = {0, 4718592, 4730880, 4733952, 4979712, 5127168, 5130240,
                       5179392, 5182464, 7541760, 7542528, 7543296};
  const void* src = sp.p[0];
  int base = 0;
#pragma unroll
  for (int k = 1; k <= 10; k++) {
    if (i >= off[k]) { src = sp.p[k]; base = off[k]; }
  }
  int j = i - base;
  float v = (*flagp) ? (float)((const bf16_t*)src)[j] : ((const float*)src)[j];
  wk[i] = (bf16_t)v;
}

// ---------------------------------------------------------------------------
// x_proj weight pad: (2 layers, 80,1536) -> (2 layers, 128,1536), zero rows
// 80..127. Lets x_proj run as a standard 128-wide MFMA GEMM n-block.
// ---------------------------------------------------------------------------
__global__ __launch_bounds__(256) void pad_xpw(const bf16_t* __restrict__ src,
                                               bf16_t* __restrict__ dst) {
  int i = blockIdx.x * 256 + threadIdx.x;       // 2*128*1536
  if (i >= 2 * 128 * 1536) return;
  int c = i % 1536;
  int r = (i / 1536) % 128;
  int lay = i / (128 * 1536);
  dst[i] = (r < 80) ? src[((size_t)lay * 80 + r) * 1536 + c] : (bf16_t)0.f;
}

// ---------------------------------------------------------------------------
// Optional: full embedding table -> bf16 (only if d_ws is big enough).
// ---------------------------------------------------------------------------
__global__ __launch_bounds__(256) void cvt_emb(const void* __restrict__ src,
                                               bf16_t* __restrict__ dst,
                                               const int* __restrict__ flagp) {
  int i = blockIdx.x * 256 + threadIdx.x;      // chunk of 8 elements
  const int nchunk = 32000 * 768 / 8;
  if (i >= nchunk) return;
  if (*flagp) {
    ((uint4*)dst)[i] = ((const uint4*)src)[i];
  } else {
    const float4* s = (const float4*)src + (size_t)i * 2;
    float4 f0 = s[0], f1 = s[1];
    bf16x8 v;
    v[0] = (bf16_t)f0.x; v[1] = (bf16_t)f0.y; v[2] = (bf16_t)f0.z; v[3] = (bf16_t)f0.w;
    v[4] = (bf16_t)f1.x; v[5] = (bf16_t)f1.y; v[6] = (bf16_t)f1.z; v[7] = (bf16_t)f1.w;
    *(bf16x8*)(dst + (size_t)i * 8) = v;
  }
}

// ---------------------------------------------------------------------------
// Embedding gather: h (f32 residual stream) and hb (bf16 GEMM A-operand).
// ---------------------------------------------------------------------------
__global__ __launch_bounds__(256) void embed_kernel(const int* __restrict__ x,
                                                    const void* __restrict__ emb,
                                                    float* __restrict__ h,
                                                    bf16_t* __restrict__ hb,
                                                    const int* __restrict__ flagp) {
  int isbf = *flagp;
  int idx = blockIdx.x * 256 + threadIdx.x;           // 2048*768
  if (idx >= NROWS * D_MODEL) return;
  int row = idx / D_MODEL, c = idx - row * D_MODEL;
  size_t o = (size_t)x[row] * D_MODEL + c;
  float v = isbf ? (float)((const bf16_t*)emb)[o] : ((const float*)emb)[o];
  h[idx] = v;
  hb[idx] = (bf16_t)v;
}

// ---------------------------------------------------------------------------
// MFMA GEMM: C(M,N) = A(M,K) * Bw(N,K)^T. A always bf16 (16B-aligned rows).
// K must be a multiple of 64. BK=64, linear LDS, global_load_lds dwordx4
// with XOR chunk swizzle (source+read sides; rule 21).
// mode 0: Cf = acc; mode 1: v=acc+res -> Cf,Cb; mode 2: Cf = acc (fp32 out)
// mode 3: Cf[row*80+col] = acc, only col<80  [x_proj into xdbl, stride 80]
// swapgrid 0: nb=bx, mb=by.  1: mb=bx, nb=by.
// swapgrid 2: XCD-chunked bijective remap (requires gridDim.x==16 and
//   nwg%8==0): each XCD gets a contiguous run of m-fastest blocks so all 16
//   sharers of a B panel sit on ONE XCD's L2 (T1 + panel-reuse combined).
// ---------------------------------------------------------------------------
typedef __attribute__((address_space(3))) void lds_void_t;
typedef __attribute__((address_space(1))) void glb_void_t;

__device__ __forceinline__ void gload16(const void* g, void* l) {
  __builtin_amdgcn_global_load_lds((const glb_void_t*)(unsigned long long)g,
                                   (lds_void_t*)(unsigned long long)l, 16, 0, 0);
}

__global__ __launch_bounds__(256) void gemm_bt(const bf16_t* __restrict__ A,
                                               const void* __restrict__ Bw,
                                               int M, int N, int K, int mode,
                                               float* __restrict__ Cf,
                                               bf16_t* __restrict__ Cb,
                                               const float* __restrict__ res,
                                               const int* __restrict__ flagp,
                                               int swapgrid) {
  __shared__ __align__(16) bf16_t As[128 * 64];
  __shared__ __align__(16) bf16_t Bs[128 * 64];
  int bNative = flagp ? (*flagp == 0) : 0;      // 1 -> Bw is fp32
  int tid = threadIdx.x;
  int mb, nb;
  if (swapgrid == 2) {
    int nwg = gridDim.x * gridDim.y;            // multiple of 8
    int lin = blockIdx.y * gridDim.x + blockIdx.x;
    int cpx = nwg >> 3;
    int nid = (lin & 7) * cpx + (lin >> 3);
    mb = nid & 15;                              // gridDim.x == 16
    nb = nid >> 4;
  } else if (swapgrid == 1) {
    mb = blockIdx.x; nb = blockIdx.y;
  } else {
    nb = blockIdx.x; mb = blockIdx.y;
  }
  int m0 = mb * 128, n0 = nb * 128;
  int wave = tid >> 6, lane = tid & 63;
  int wr = wave >> 1, wc = wave & 1;
  int m16 = lane & 15, ksel = lane >> 4;
  int srow = lane >> 3;                         // 0..7 within an 8-row slab
  int sseg = lane & 7;

  floatx4 acc[4][4];
#pragma unroll
  for (int i = 0; i < 4; i++)
#pragma unroll
    for (int j = 0; j < 4; j++) acc[i][j] = (floatx4){0.f, 0.f, 0.f, 0.f};

  for (int k0 = 0; k0 < K; k0 += 64) {
#pragma unroll
    for (int i = 0; i < 4; i++) {
      int j = wave * 4 + i;
      int row = j * 8 + srow;
      int sg = sseg ^ (row & 7);
      gload16(A + (size_t)(m0 + row) * K + k0 + sg * 8, &As[j * 512]);
    }
    if (!bNative) {
#pragma unroll
      for (int i = 0; i < 4; i++) {
        int j = wave * 4 + i;
        int row = j * 8 + srow;
        int sg = sseg ^ (row & 7);
        gload16((const bf16_t*)Bw + (size_t)(n0 + row) * K + k0 + sg * 8, &Bs[j * 512]);
      }
    } else {
#pragma unroll
      for (int rep = 0; rep < 4; rep++) {
        int l = tid + rep * 256;
        int row = l >> 3, sg = l & 7;
        const float* gb = (const float*)Bw + (size_t)(n0 + row) * K + k0 + sg * 8;
        float4 f0 = *(const float4*)gb;
        float4 f1 = *(const float4*)(gb + 4);
        bf16x8 v;
        v[0] = (bf16_t)f0.x; v[1] = (bf16_t)f0.y; v[2] = (bf16_t)f0.z; v[3] = (bf16_t)f0.w;
        v[4] = (bf16_t)f1.x; v[5] = (bf16_t)f1.y; v[6] = (bf16_t)f1.z; v[7] = (bf16_t)f1.w;
        *(bf16x8*)&Bs[row * 64 + (sg ^ (row & 7)) * 8] = v;
      }
    }
    __syncthreads();
#pragma unroll
    for (int kk = 0; kk < 2; kk++) {
      int ck = (ksel + 4 * kk) ^ (lane & 7);
      bf16x8 aF[4], bF[4];
#pragma unroll
      for (int mi = 0; mi < 4; mi++)
        aF[mi] = *(const bf16x8*)&As[(wr * 64 + mi * 16 + m16) * 64 + ck * 8];
#pragma unroll
      for (int ni = 0; ni < 4; ni++)
        bF[ni] = *(const bf16x8*)&Bs[(wc * 64 + ni * 16 + m16) * 64 + ck * 8];
#pragma unroll
      for (int mi = 0; mi < 4; mi++)
#pragma unroll
        for (int ni = 0; ni < 4; ni++)
          acc[mi][ni] = __builtin_amdgcn_mfma_f32_16x16x32_bf16(aF[mi], bF[ni], acc[mi][ni], 0, 0, 0);
    }
    __syncthreads();
  }

#pragma unroll
  for (int mi = 0; mi < 4; mi++)
#pragma unroll
    for (int ni = 0; ni < 4; ni++)
#pragma unroll
      for (int r = 0; r < 4; r++) {
        int row = m0 + wr * 64 + mi * 16 + ksel * 4 + r;
        int col = n0 + wc * 64 + ni * 16 + m16;
        size_t off = (size_t)row * N + col;
        float v = acc[mi][ni][r];
        if (mode == 0) {
          Cf[off] = v;
        } else if (mode == 1) {
          float o = v + res[off];
          Cf[off] = o;
          Cb[off] = (bf16_t)o;
        } else if (mode == 2) {
          Cf[off] = v;
        } else {                    // mode 3: xdbl, row stride 80, cols<80
          if (col < 80) Cf[(size_t)row * 80 + col] = v;
        }
      }
}

// ---------------------------------------------------------------------------
// Depthwise causal conv1d (K=4) + bias + SiLU. x_in = xz[:, 0:1536] (f32).
// ---------------------------------------------------------------------------
__global__ __launch_bounds__(256) void conv_silu(const float* __restrict__ xz,
                                                 const bf16_t* __restrict__ cw,
                                                 const bf16_t* __restrict__ cb,
                                                 bf16_t* __restrict__ xc) {
  int idx = blockIdx.x * 256 + threadIdx.x;   // NROWS*D_INNER
  if (idx >= NROWS * D_INNER) return;
  int d = idx % D_INNER;
  int row = idx / D_INNER;
  int l = row % LSEQ;
  int base = row - l;                         // start row of this batch
  float s = (float)cb[d];
#pragma unroll
  for (int k = 0; k < 4; k++) {
    int ll = l - 3 + k;
    if (ll >= 0) s += (float)cw[d * 4 + k] * xz[(size_t)(base + ll) * (2 * D_INNER) + d];
  }
  float sil = s / (1.f + __expf(-s));
  xc[idx] = (bf16_t)sil;
}

// ---------------------------------------------------------------------------
// dt_proj + softplus: dt(2048,1536) = softplus(x_dbl[:, :48] @ W(1536,48)^T + b)
// Vectorized: 6x bf16x8 weight loads, 12x float4 x loads (G13).
// ---------------------------------------------------------------------------
__global__ __launch_bounds__(256) void dtproj_kernel(const float* __restrict__ xdbl,
                                                     const bf16_t* __restrict__ W,
                                                     const bf16_t* __restrict__ bias,
                                                     float* __restrict__ dt) {
  int idx = blockIdx.x * 256 + threadIdx.x;  // NROWS*D_INNER
  if (idx >= NROWS * D_INNER) return;
  int d = idx % D_INNER;
  int row = idx / D_INNER;
  const bf16x8* w8 = (const bf16x8*)(W + (size_t)d * DT_RANK);   // 96B rows, 16B-aligned
  const float4* x4 = (const float4*)(xdbl + (size_t)row * 80);
  float s = (float)bias[d];
#pragma unroll
  for (int q = 0; q < 6; q++) {
    bf16x8 w = w8[q];
    float4 a = x4[q * 2], b = x4[q * 2 + 1];
    s = fmaf(a.x, (float)w[0], s); s = fmaf(a.y, (float)w[1], s);
    s = fmaf(a.z, (float)w[2], s); s = fmaf(a.w, (float)w[3], s);
    s = fmaf(b.x, (float)w[4], s); s = fmaf(b.y, (float)w[5], s);
    s = fmaf(b.z, (float)w[6], s); s = fmaf(b.w, (float)w[7], s);
  }
  float sp = (s > 20.f) ? s : log1pf(__expf(s));
  dt[idx] = sp;
}

// ---------------------------------------------------------------------------
// Chunked selective scan (3 phases). lane = channel d (coalesced streams),
// 16 n-states in registers, L split into 32 chunks of 32 rows.
// Phase1: per chunk, P = prod(dA), F = h(end | h_start=0)   per (d,n)
// Phase2: h_in(c) = P(c-1)*h_in(c-1) + F(c-1)               (serial, tiny)
// Phase3: re-scan chunk seeded with h_in; y = sum_n h*C + D*u, SiLU(z) gate.
// ---------------------------------------------------------------------------
__global__ __launch_bounds__(64) void scan_p1(const float* __restrict__ dt_,
                                              const bf16_t* __restrict__ xc,
                                              const float* __restrict__ xdbl,
                                              const bf16_t* __restrict__ A_log,
                                              float* __restrict__ P,
                                              float* __restrict__ F) {
  int wg = blockIdx.x;                 // 0..1535
  int dgrp = wg % SCAN_NDG, c2 = wg / SCAN_NDG;   // c2 = b*32+c, 0..63
  int b = c2 >> 5, c = c2 & 31;
  int d = dgrp * 64 + threadIdx.x;
  int r0 = b * LSEQ + c * SCAN_RPC;

  float Adn[16];
  {
    bf16x8 a0 = *(const bf16x8*)(A_log + (size_t)d * 16);
    bf16x8 a1 = *(const bf16x8*)(A_log + (size_t)d * 16 + 8);
#pragma unroll
    for (int n = 0; n < 8; n++) { Adn[n] = -__expf((float)a0[n]); Adn[n + 8] = -__expf((float)a1[n]); }
  }
  float h[16], p[16];
#pragma unroll
  for (int n = 0; n < 16; n++) { h[n] = 0.f; p[n] = 1.f; }

  float dtv = dt_[(size_t)r0 * D_INNER + d];
  float uv = (float)xc[(size_t)r0 * D_INNER + d];
  float Bv[16];
  {
    const float4* bp = (const float4*)(xdbl + (size_t)r0 * 80 + DT_RANK);
#pragma unroll
    for (int q = 0; q < 4; q++) *(float4*)&Bv[q * 4] = bp[q];
  }

  for (int i = 0; i < SCAN_RPC; i++) {
    int rn = r0 + i + 1;               // depth-1 prefetch (over-read OK)
    float dtn = dt_[(size_t)rn * D_INNER + d];
    float un = (float)xc[(size_t)rn * D_INNER + d];
    float Bn[16];
    {
      const float4* bp = (const float4*)(xdbl + (size_t)rn * 80 + DT_RANK);
#pragma unroll
      for (int q = 0; q < 4; q++) *(float4*)&Bn[q * 4] = bp[q];
    }
    float dtu = dtv * uv;
#pragma unroll
    for (int n = 0; n < 16; n++) {
      float dA = __expf(dtv * Adn[n]);
      h[n] = fmaf(dA, h[n], dtu * Bv[n]);
      p[n] *= dA;
    }
    dtv = dtn; uv = un;
#pragma unroll
    for (int n = 0; n < 16; n++) Bv[n] = Bn[n];
  }

  size_t o = (size_t)c2 * SCAN_STRIDE + (size_t)d * 16;
#pragma unroll
  for (int q = 0; q < 4; q++) {
    *(float4*)(P + o + q * 4) = *(float4*)&p[q * 4];
    *(float4*)(F + o + q * 4) = *(float4*)&h[q * 4];
  }
}

__global__ __launch_bounds__(256) void scan_p2(const float* __restrict__ P,
                                               const float* __restrict__ F,
                                               float* __restrict__ Hin) {
  int gid = blockIdx.x * 256 + threadIdx.x;   // < 49152 = 2*24576
  if (gid >= 2 * SCAN_STRIDE) return;
  int b = gid / SCAN_STRIDE, j = gid - b * SCAN_STRIDE;
  float pP[SCAN_C], pF[SCAN_C];
#pragma unroll
  for (int c = 0; c < SCAN_C; c++) {
    size_t o = (size_t)(b * SCAN_C + c) * SCAN_STRIDE + j;
    pP[c] = P[o]; pF[c] = F[o];
  }
  float h = 0.f;
#pragma unroll
  for (int c = 0; c < SCAN_C; c++) {
    size_t o = (size_t)(b * SCAN_C + c) * SCAN_STRIDE + j;
    Hin[o] = h;
    h = fmaf(pP[c], h, pF[c]);
  }
}

__global__ __launch_bounds__(64) void scan_p3(const float* __restrict__ dt_,
                                              const bf16_t* __restrict__ xc,
                                              const float* __restrict__ xdbl,
                                              const float* __restrict__ xz,
                                              const bf16_t* __restrict__ A_log,
                                              const bf16_t* __restrict__ Dp,
                                              const float* __restrict__ Hin,
                                              bf16_t* __restrict__ yg) {
  int wg = blockIdx.x;
  int dgrp = wg % SCAN_NDG, c2 = wg / SCAN_NDG;
  int b = c2 >> 5, c = c2 & 31;
  int d = dgrp * 64 + threadIdx.x;
  int r0 = b * LSEQ + c * SCAN_RPC;

  float Adn[16];
  {
    bf16x8 a0 = *(const bf16x8*)(A_log + (size_t)d * 16);
    bf16x8 a1 = *(const bf16x8*)(A_log + (size_t)d * 16 + 8);
#pragma unroll
    for (int n = 0; n < 8; n++) { Adn[n] = -__expf((float)a0[n]); Adn[n + 8] = -__expf((float)a1[n]); }
  }
  float Dd = (float)Dp[d];
  float h[16];
  {
    size_t o = (size_t)c2 * SCAN_STRIDE + (size_t)d * 16;
#pragma unroll
    for (int q = 0; q < 4; q++) *(float4*)&h[q * 4] = *(const float4*)(Hin + o + q * 4);
  }

  float dtv = dt_[(size_t)r0 * D_INNER + d];
  float uv = (float)xc[(size_t)r0 * D_INNER + d];
  float zv = xz[(size_t)r0 * (2 * D_INNER) + D_INNER + d];
  float Bv[16], Cv[16];
  {
    const float4* bp = (const float4*)(xdbl + (size_t)r0 * 80 + DT_RANK);
#pragma unroll
    for (int q = 0; q < 4; q++) *(float4*)&Bv[q * 4] = bp[q];
#pragma unroll
    for (int q = 0; q < 4; q++) *(float4*)&Cv[q * 4] = bp[q + 4];
  }

  for (int i = 0; i < SCAN_RPC; i++) {
    int r = r0 + i;
    int rn = r + 1;                    // depth-1 prefetch (over-read OK)
    float dtn = dt_[(size_t)rn * D_INNER + d];
    float un = (float)xc[(size_t)rn * D_INNER + d];
    float zn = xz[(size_t)rn * (2 * D_INNER) + D_INNER + d];
    float Bn[16], Cn[16];
    {
      const float4* bp = (const float4*)(xdbl + (size_t)rn * 80 + DT_RANK);
#pragma unroll
      for (int q = 0; q < 4; q++) *(float4*)&Bn[q * 4] = bp[q];
#pragma unroll
      for (int q = 0; q < 4; q++) *(float4*)&Cn[q * 4] = bp[q + 4];
    }
    float dtu = dtv * uv;
    float y = 0.f;
#pragma unroll
    for (int n = 0; n < 16; n++) {
      float dA = __expf(dtv * Adn[n]);
      h[n] = fmaf(dA, h[n], dtu * Bv[n]);
      y = fmaf(h[n], Cv[n], y);
    }
    float sil = zv / (1.f + __expf(-zv));
    yg[(size_t)r * D_INNER + d] = (bf16_t)((y + Dd * uv) * sil);
    dtv = dtn; uv = un; zv = zn;
#pragma unroll
    for (int n = 0; n < 16; n++) { Bv[n] = Bn[n]; Cv[n] = Cn[n]; }
  }
}

// ---------------------------------------------------------------------------
// LayerNorm over 768, bf16 out (logits A-operand).
// ---------------------------------------------------------------------------
__global__ __launch_bounds__(256) void ln_kernel(const float* __restrict__ h,
                                                 const bf16_t* __restrict__ w,
                                                 const bf16_t* __restrict__ b,
                                                 bf16_t* __restrict__ out) {
  __shared__ float s1[4], s2[4];
  int row = blockIdx.x;
  int tid = threadIdx.x, lane = tid & 63, wave = tid >> 6;
  const float* hr = h + (size_t)row * D_MODEL;
  float a = 0.f, a2 = 0.f;
  for (int i = tid; i < D_MODEL; i += 256) {
    float v = hr[i];
    a += v; a2 += v * v;
  }
#pragma unroll
  for (int m = 32; m >= 1; m >>= 1) {
    a += __shfl_xor(a, m, 64);
    a2 += __shfl_xor(a2, m, 64);
  }
  if (lane == 0) { s1[wave] = a; s2[wave] = a2; }
  __syncthreads();
  float sum = s1[0] + s1[1] + s1[2] + s1[3];
  float sum2 = s2[0] + s2[1] + s2[2] + s2[3];
  float mu = sum / D_MODEL;
  float var = sum2 / D_MODEL - mu * mu;
  float inv = rsqrtf(var + 1e-5f);
  for (int i = tid; i < D_MODEL; i += 256)
    out[(size_t)row * D_MODEL + i] = (bf16_t)((hr[i] - mu) * inv * (float)w[i] + (float)b[i]);
}

// ---------------------------------------------------------------------------
extern "C" void kernel_launch(void* const* d_in, const int* in_sizes, int n_in,
                              void* d_out, int out_size, void* d_ws, size_t ws_size,
                              hipStream_t stream) {
  const int* x = (const int*)d_in[0];
  const void* emb = d_in[1];
  float* out = (float*)d_out;                    // OUTPUT IS FP32 (reference dtype)

  // --- scratch inside d_out (dead before the final logits GEMM writes it) ---
  char* ob = (char*)d_out;
  float* h = (float*)(ob + 0);                   //  6,291,456 B
  bf16_t* hb = (bf16_t*)(ob + 6291456);          //  3,145,728 B
  float* xz = (float*)(ob + 9437184);            // 25,165,824 B
  bf16_t* xc = (bf16_t*)(ob + 34603008);         //  6,291,456 B
  float* xdbl = (float*)(ob + 40894464);         //    655,360 B
  float* dt = (float*)(ob + 41549824);           // 12,582,912 B
  bf16_t* yg = (bf16_t*)(ob + 54132736);         //  6,291,456 B
  bf16_t* wk = (bf16_t*)(ob + 60424192);         // 15,086,592 B canonical bf16 weights
  bf16_t* c_xpwp = (bf16_t*)(ob + 75510784);     //    786,432 B padded x_proj W (2x128x1536)
  float* scanP = (float*)(ob + 76297216);        //  6,291,456 B
  float* scanF = (float*)(ob + 82588672);        //  6,291,456 B
  float* scanH = (float*)(ob + 88880128);        //  6,291,456 B (ends 95.2 MB < 262 MB)
  // --- d_ws: data that must survive the logits GEMM + dtype flag ---
  bf16_t* lno = (bf16_t*)d_ws;                   //  3,145,728 B
  int* flag = (int*)((char*)d_ws + 3145728);
  bf16_t* embb = (bf16_t*)((char*)d_ws + 3145744); // 49,152,000 B (optional)
  bool bigws = ws_size >= (size_t)3145744 + 49152000u;

  // canonical weight layout (element offsets into wk)
  bf16_t* c_inw  = wk + 0;          // 2*3072*768 = 4,718,592
  bf16_t* c_cw   = wk + 4718592;    // 12,288
  bf16_t* c_cb   = wk + 4730880;    // 3,072
  bf16_t* c_xpw  = wk + 4733952;    // 245,760
  bf16_t* c_dtw  = wk + 4979712;    // 147,456
  bf16_t* c_dtb  = wk + 5127168;    // 3,072
  bf16_t* c_alog = wk + 5130240;    // 49,152
  bf16_t* c_dp   = wk + 5179392;    // 3,072
  bf16_t* c_outw = wk + 5182464;    // 2,359,296
  bf16_t* c_lnw  = wk + 7541760;    // 768
  bf16_t* c_lnb  = wk + 7542528;    // 768

  detect_kernel<<<1, 64, 0, stream>>>((const unsigned int*)d_in[11], flag);

  CvtSrcs srcs;
  for (int k = 0; k < 11; k++) srcs.p[k] = d_in[k + 2];
  const int cvt_total = 7543296;
  cvt_all<<<(cvt_total + 255) / 256, 256, 0, stream>>>(srcs, wk, cvt_total, flag);
  pad_xpw<<<(2 * 128 * 1536 + 255) / 256, 256, 0, stream>>>(c_xpw, c_xpwp);

  if (bigws)
    cvt_emb<<<(32000 * 768 / 8 + 255) / 256, 256, 0, stream>>>(emb, embb, flag);

  embed_kernel<<<(NROWS * D_MODEL + 255) / 256, 256, 0, stream>>>(x, emb, h, hb, flag);

  for (int i = 0; i < 2; i++) {
    // in_proj: grid (16 m-blocks, 24 n-blocks), XCD-chunked (384%8==0)
    gemm_bt<<<dim3(16, 3072 / 128), 256, 0, stream>>>(
        hb, c_inw + (size_t)i * 2 * D_INNER * D_MODEL, NROWS, 2 * D_INNER, D_MODEL,
        0, xz, nullptr, nullptr, nullptr, 2);
    conv_silu<<<(NROWS * D_INNER + 255) / 256, 256, 0, stream>>>(
        xz, c_cw + (size_t)i * D_INNER * 4, c_cb + (size_t)i * D_INNER, xc);
    // x_proj as MFMA GEMM: N=128 (padded W), writes xdbl (stride 80, col<80)
    gemm_bt<<<dim3(1, NROWS / 128), 256, 0, stream>>>(
        xc, c_xpwp + (size_t)i * 128 * D_INNER, NROWS, 128, D_INNER,
        3, xdbl, nullptr, nullptr, nullptr, 0);
    dtproj_kernel<<<(NROWS * D_INNER + 255) / 256, 256, 0, stream>>>(
        xdbl, c_dtw + (size_t)i * D_INNER * DT_RANK, c_dtb + (size_t)i * D_INNER, dt);
    scan_p1<<<2 * SCAN_C * SCAN_NDG, 64, 0, stream>>>(
        dt, xc, xdbl, c_alog + (size_t)i * D_INNER * D_STATE, scanP, scanF);
    scan_p2<<<(2 * SCAN_STRIDE + 255) / 256, 256, 0, stream>>>(scanP, scanF, scanH);
    scan_p3<<<2 * SCAN_C * SCAN_NDG, 64, 0, stream>>>(
        dt, xc, xdbl, xz, c_alog + (size_t)i * D_INNER * D_STATE,
        c_dp + (size_t)i * D_INNER, scanH, yg);
    // out_proj: grid (16 m-blocks, 6 n-blocks), XCD-chunked (96%8==0)
    gemm_bt<<<dim3(16, D_MODEL / 128), 256, 0, stream>>>(
        yg, c_outw + (size_t)i * D_MODEL * D_INNER, NROWS, D_MODEL, D_INNER,
        1, h, hb, h, nullptr, 2);
  }

  ln_kernel<<<NROWS, 256, 0, stream>>>(h, c_lnw, c_lnb, lno);

  // logits (fp32) = lno @ emb^T. grid (16 m-blocks, 250 n-blocks),
  // XCD-chunked (4000%8==0): all 16 sharers of a B panel on one XCD L2.
  if (bigws)
    gemm_bt<<<dim3(16, 32000 / 128), 256, 0, stream>>>(
        lno, embb, NROWS, 32000, D_MODEL, 2, out, nullptr, nullptr, nullptr, 2);
  else
    gemm_bt<<<dim3(16, 32000 / 128), 256, 0, stream>>>(
        lno, emb, NROWS, 32000, D_MODEL, 2, out, nullptr, nullptr, flag, 2);
}